// Round 4
// baseline (3510.262 us; speedup 1.0000x reference)
//
#include <hip/hip_runtime.h>
#include <hip/hip_bf16.h>
#include <cstdint>
#include <cstddef>

#define S_LEN   2048
#define NHQ     16
#define NKV_H   8
#define HD_DIM  128
#define DMODEL  2048
#define BATCH   2
#define KVD     (NKV_H * HD_DIM)   // 1024

// ---------------------------------------------------------------------------
// Dtype sniff for x: bf16 (flag=1) or f32 (flag=0)? Reads first 1024 dwords.
// ---------------------------------------------------------------------------
__global__ void sniff_x_kernel(const unsigned* __restrict__ x,
                               int* __restrict__ flag) {
    __shared__ int cnt;
    if (threadIdx.x == 0) cnt = 0;
    __syncthreads();
    int c = 0;
    for (int j = threadIdx.x; j < 1024; j += 256) {
        unsigned hw = x[j] & 0xFFFFu;
        unsigned e  = (hw >> 7) & 0xFF;
        if (hw == 0u || (e >= 118 && e <= 132)) c++;
    }
    atomicAdd(&cnt, c);
    __syncthreads();
    if (threadIdx.x == 0) *flag = (cnt > 512) ? 1 : 0;
}

// ---------------------------------------------------------------------------
// Dtype sniff for freqs_cos: row s=0 is exactly 1.0 everywhere.
// ---------------------------------------------------------------------------
__global__ void sniff_fc_kernel(const unsigned* __restrict__ fc,
                                int* __restrict__ flag) {
    if (threadIdx.x == 0) *flag = (fc[0] == 0x3F803F80u) ? 1 : 0;
}

// ---------------------------------------------------------------------------
// Mask normalization with layout sniffing (u8 / i32 / f32 / bf16).
// ---------------------------------------------------------------------------
__global__ void mask_norm_kernel(const unsigned char* __restrict__ mraw,
                                 unsigned char* __restrict__ mout, int n) {
    __shared__ int f_bf16, f_f32, f_u8;
    if (threadIdx.x == 0) { f_bf16 = 0; f_f32 = 0; f_u8 = 0; }
    __syncthreads();
    const unsigned* dw = (const unsigned*)mraw;
    int ndw = n / 4;
    for (int j = threadIdx.x; j < ndw; j += blockDim.x) {
        unsigned v = dw[j];
        if (v == 0x00003F80u || v == 0x3F803F80u) f_bf16 = 1;
        else if (v == 0x3F800000u) f_f32 = 1;
        else if (v & 0xFFFFFFFEu) f_u8 = 1;
    }
    __syncthreads();
    int layout;              // 0=u8 1=i32 2=f32 3=bf16
    if (f_bf16) layout = 3;
    else if (f_f32) layout = 2;
    else if (f_u8) layout = 0;
    else layout = 1;
    for (int i = threadIdx.x; i < n; i += blockDim.x) {
        unsigned v;
        if (layout == 0)      v = mraw[i];
        else if (layout == 3) v = ((const unsigned short*)mraw)[i];
        else                  v = ((const unsigned*)mraw)[i];
        mout[i] = v ? 1u : 0u;
    }
}

// ---------------------------------------------------------------------------
// Load 8 contiguous elements as f32 from either a bf16 or f32 buffer.
// ---------------------------------------------------------------------------
__device__ __forceinline__ void load8_f32(const void* base, size_t off,
                                          int is_bf16, float v[8]) {
    if (is_bf16) {
        uint4 u = *reinterpret_cast<const uint4*>((const __hip_bfloat16*)base + off);
        unsigned w[4] = {u.x, u.y, u.z, u.w};
#pragma unroll
        for (int i = 0; i < 4; ++i) {
            v[2 * i]     = __uint_as_float(w[i] << 16);
            v[2 * i + 1] = __uint_as_float(w[i] & 0xFFFF0000u);
        }
    } else {
        const float4* f = reinterpret_cast<const float4*>((const float*)base + off);
        float4 a = f[0], b = f[1];
        v[0] = a.x; v[1] = a.y; v[2] = a.z; v[3] = a.w;
        v[4] = b.x; v[5] = b.y; v[6] = b.z; v[7] = b.w;
    }
}

// ---------------------------------------------------------------------------
// Tiled GEMM, C[M,N] = A[M,K] @ Bw[N,K]^T, fp32 accumulate.
// a_mode/b_mode: 0 = f32, 1 = bf16, 2 = per *dflag. OUT_BF16 picks C dtype.
// ---------------------------------------------------------------------------
template <bool OUT_BF16>
__global__ __launch_bounds__(256)
void gemm_bt_kernel(const void* __restrict__ A, const void* __restrict__ Bw,
                    void* __restrict__ Cv, int M, int N, int K,
                    const int* __restrict__ dflag, int a_mode, int b_mode) {
    __shared__ float As[32][68];
    __shared__ float Bs[32][68];
    const int abf = (a_mode == 2) ? *dflag : a_mode;
    const int bbf = (b_mode == 2) ? *dflag : b_mode;
    const int t  = threadIdx.x;
    const int tx = t & 15, ty = t >> 4;
    const int m0 = blockIdx.x * 64, n0 = blockIdx.y * 64;
    const int row = t >> 2;
    const int kc  = (t & 3) * 8;
    float acc[4][4] = {};

    for (int k0 = 0; k0 < K; k0 += 32) {
        float va[8], vb[8];
        load8_f32(A,  (size_t)(m0 + row) * K + (k0 + kc), abf, va);
        load8_f32(Bw, (size_t)(n0 + row) * K + (k0 + kc), bbf, vb);
#pragma unroll
        for (int j = 0; j < 8; ++j) As[kc + j][row] = va[j];
#pragma unroll
        for (int j = 0; j < 8; ++j) Bs[kc + j][row] = vb[j];
        __syncthreads();
#pragma unroll
        for (int kk = 0; kk < 32; ++kk) {
            float4 a = *reinterpret_cast<const float4*>(&As[kk][ty * 4]);
            float4 b = *reinterpret_cast<const float4*>(&Bs[kk][tx * 4]);
            float av[4] = {a.x, a.y, a.z, a.w};
            float bv[4] = {b.x, b.y, b.z, b.w};
#pragma unroll
            for (int i = 0; i < 4; ++i)
#pragma unroll
                for (int j = 0; j < 4; ++j) acc[i][j] += av[i] * bv[j];
        }
        __syncthreads();
    }
#pragma unroll
    for (int i = 0; i < 4; ++i) {
        int m = m0 + ty * 4 + i;
#pragma unroll
        for (int j = 0; j < 4; ++j) {
            int n = n0 + tx * 4 + j;
            if constexpr (OUT_BF16)
                ((__hip_bfloat16*)Cv)[(size_t)m * N + n] = __float2bfloat16(acc[i][j]);
            else
                ((float*)Cv)[(size_t)m * N + n] = acc[i][j];
        }
    }
}

// ---------------------------------------------------------------------------
// RoPE in-place on bf16 [B*S, nheads*128]; pair i rotates (2i, 2i+1).
// ---------------------------------------------------------------------------
__global__ void rope_kernel(__hip_bfloat16* __restrict__ xqk,
                            const void* __restrict__ cosv,
                            const void* __restrict__ sinv,
                            const int* __restrict__ dflag_fc,
                            int nheads, int npairs) {
    int idx = blockIdx.x * blockDim.x + threadIdx.x;
    if (idx >= npairs) return;
    int i  = idx & 63;
    int h  = (idx >> 6) % nheads;
    int bs = idx / (64 * nheads);
    int s  = bs & (S_LEN - 1);
    float c, sn;
    if (*dflag_fc) {
        c  = __bfloat162float(((const __hip_bfloat16*)cosv)[s * 64 + i]);
        sn = __bfloat162float(((const __hip_bfloat16*)sinv)[s * 64 + i]);
    } else {
        c  = ((const float*)cosv)[s * 64 + i];
        sn = ((const float*)sinv)[s * 64 + i];
    }
    unsigned* p = (unsigned*)(xqk + (size_t)bs * (nheads * HD_DIM) + h * HD_DIM) + i;
    unsigned u = *p;
    float xr = __uint_as_float(u << 16);
    float xi = __uint_as_float(u & 0xFFFF0000u);
    float o0 = xr * c - xi * sn;
    float o1 = xr * sn + xi * c;
    union { __hip_bfloat16 h2[2]; unsigned u32; } out;
    out.h2[0] = __float2bfloat16(o0);
    out.h2[1] = __float2bfloat16(o1);
    *p = out.u32;
}

// ---------------------------------------------------------------------------
// Flash-style attention, online softmax. Block = 8 q rows of one (b,h).
// att may ALIAS xq: each block writes exactly the 8x128 region only it reads,
// staged to LDS (with barrier) before any write.
// ---------------------------------------------------------------------------
__global__ __launch_bounds__(256)
void attn_kernel(const __hip_bfloat16* xq,
                 const __hip_bfloat16* __restrict__ xk,
                 const __hip_bfloat16* __restrict__ xv,
                 const unsigned char* __restrict__ msk,
                 __hip_bfloat16* att) {
    __shared__ float Qs[8][128];
    __shared__ float Ks[64][132];
    __shared__ float Sc[8][64];
    __shared__ float m_s[8], l_s[8], alpha_s[8];

    const int t   = threadIdx.x;
    const int bid = blockIdx.x;
    const int qt  = bid & 255;
    const int h   = (bid >> 8) & (NHQ - 1);
    const int b   = bid >> 12;
    const int kvh = h >> 1;
    const int q0  = qt * 8;

    for (int i = t; i < 8 * 64; i += 256) {
        int r = i >> 6, dp = i & 63;
        unsigned u = ((const unsigned*)(xq + (size_t)(b * S_LEN + q0 + r) * DMODEL + h * HD_DIM))[dp];
        Qs[r][2 * dp]     = __uint_as_float(u << 16);
        Qs[r][2 * dp + 1] = __uint_as_float(u & 0xFFFF0000u);
    }
    if (t < 8) { m_s[t] = -INFINITY; l_s[t] = 0.f; alpha_s[t] = 0.f; }
    float acc0 = 0.f, acc1 = 0.f, acc2 = 0.f, acc3 = 0.f;
    const int d  = t & 127;
    const int rg = t >> 7;
    __syncthreads();

    const float scale = 0.08838834764831845f;  // 1/sqrt(128)

    for (int k0 = 0; k0 < S_LEN; k0 += 64) {
        for (int i = t; i < 64 * 64; i += 256) {
            int kk = i >> 6, dp = i & 63;
            unsigned u = ((const unsigned*)(xk + (size_t)(b * S_LEN + k0 + kk) * KVD + kvh * HD_DIM))[dp];
            Ks[kk][2 * dp]     = __uint_as_float(u << 16);
            Ks[kk][2 * dp + 1] = __uint_as_float(u & 0xFFFF0000u);
        }
        __syncthreads();
        {
            int kk = t & 63, qp = t >> 6;
            int qr0 = qp * 2, qr1 = qr0 + 1;
            float s0 = 0.f, s1 = 0.f;
#pragma unroll
            for (int dd = 0; dd < 128; dd += 4) {
                float4 kv = *reinterpret_cast<const float4*>(&Ks[kk][dd]);
                float4 qa = *reinterpret_cast<const float4*>(&Qs[qr0][dd]);
                float4 qb = *reinterpret_cast<const float4*>(&Qs[qr1][dd]);
                s0 += qa.x * kv.x + qa.y * kv.y + qa.z * kv.z + qa.w * kv.w;
                s1 += qb.x * kv.x + qb.y * kv.y + qb.z * kv.z + qb.w * kv.w;
            }
            bool m = msk[b * S_LEN + k0 + kk] != 0;
            Sc[qr0][kk] = m ? -INFINITY : s0 * scale;
            Sc[qr1][kk] = m ? -INFINITY : s1 * scale;
        }
        __syncthreads();
        {
            int r = t >> 5, c = t & 31;
            float v0 = Sc[r][c], v1 = Sc[r][c + 32];
            float mx = fmaxf(v0, v1);
#pragma unroll
            for (int o = 16; o > 0; o >>= 1) mx = fmaxf(mx, __shfl_down(mx, o, 32));
            mx = __shfl(mx, 0, 32);
            float m_old = m_s[r];
            float m_new = fmaxf(m_old, mx);
            float m_use = (m_new == -INFINITY) ? 0.f : m_new;
            float p0 = (v0 == -INFINITY) ? 0.f : expf(v0 - m_use);
            float p1 = (v1 == -INFINITY) ? 0.f : expf(v1 - m_use);
            float sum = p0 + p1;
#pragma unroll
            for (int o = 16; o > 0; o >>= 1) sum += __shfl_down(sum, o, 32);
            Sc[r][c] = p0; Sc[r][c + 32] = p1;
            if (c == 0) {
                float alpha = (m_old == -INFINITY) ? 0.f : expf(m_old - m_use);
                alpha_s[r] = alpha;
                m_s[r]     = m_new;
                l_s[r]     = l_s[r] * alpha + sum;
            }
        }
        __syncthreads();
        {
            float a0 = alpha_s[rg * 4 + 0], a1 = alpha_s[rg * 4 + 1];
            float a2 = alpha_s[rg * 4 + 2], a3 = alpha_s[rg * 4 + 3];
            acc0 *= a0; acc1 *= a1; acc2 *= a2; acc3 *= a3;
            const __hip_bfloat16* vb = xv + (size_t)(b * S_LEN + k0) * KVD + kvh * HD_DIM + d;
#pragma unroll 8
            for (int kk = 0; kk < 64; ++kk) {
                float vv = __bfloat162float(vb[(size_t)kk * KVD]);
                acc0 += Sc[rg * 4 + 0][kk] * vv;
                acc1 += Sc[rg * 4 + 1][kk] * vv;
                acc2 += Sc[rg * 4 + 2][kk] * vv;
                acc3 += Sc[rg * 4 + 3][kk] * vv;
            }
        }
        __syncthreads();
    }
    {
        float l0 = l_s[rg * 4 + 0], l1 = l_s[rg * 4 + 1];
        float l2 = l_s[rg * 4 + 2], l3 = l_s[rg * 4 + 3];
        float o0 = (l0 > 0.f) ? acc0 / l0 : 0.f;
        float o1 = (l1 > 0.f) ? acc1 / l1 : 0.f;
        float o2 = (l2 > 0.f) ? acc2 / l2 : 0.f;
        float o3 = (l3 > 0.f) ? acc3 / l3 : 0.f;
        size_t base = (size_t)(b * S_LEN + q0 + rg * 4) * DMODEL + h * HD_DIM + d;
        att[base]              = __float2bfloat16(o0);
        att[base + DMODEL]     = __float2bfloat16(o1);
        att[base + 2 * DMODEL] = __float2bfloat16(o2);
        att[base + 3 * DMODEL] = __float2bfloat16(o3);
    }
}

// ---------------------------------------------------------------------------
extern "C" void kernel_launch(void* const* d_in, const int* in_sizes, int n_in,
                              void* d_out, int out_size, void* d_ws, size_t ws_size,
                              hipStream_t stream) {
    const void* x  = d_in[0];
    const void* wq = d_in[1];
    const void* wk = d_in[2];
    const void* wv = d_in[3];
    const void* wo = d_in[4];
    const void* fc = d_in[5];
    const void* fs = d_in[6];
    const unsigned char* mraw = (const unsigned char*)d_in[7];

    const int M = BATCH * S_LEN;                                 // 4096
    // ws layout: control block first, then bf16 tensors. Total = 8 KB + 32 MB.
    char* wsb = (char*)d_ws;
    int* dflag_x  = (int*)wsb;                                   // @0
    int* dflag_fc = (int*)(wsb + 64);                            // @64
    unsigned char* mnorm = (unsigned char*)(wsb + 128);          // @128, 4 KB
    __hip_bfloat16* xq = (__hip_bfloat16*)(wsb + 8192);          // 16 MB (att aliases)
    __hip_bfloat16* xk = xq + (size_t)M * DMODEL;                // 8 MB
    __hip_bfloat16* xv = xk + (size_t)M * KVD;                   // 8 MB
    __hip_bfloat16* att = xq;                                    // alias (safe, see attn)

    hipLaunchKernelGGL(sniff_x_kernel, dim3(1), dim3(256), 0, stream,
                       (const unsigned*)x, dflag_x);
    hipLaunchKernelGGL(sniff_fc_kernel, dim3(1), dim3(64), 0, stream,
                       (const unsigned*)fc, dflag_fc);
    hipLaunchKernelGGL(mask_norm_kernel, dim3(1), dim3(256), 0, stream,
                       mraw, mnorm, BATCH * S_LEN);

    hipLaunchKernelGGL((gemm_bt_kernel<true>), dim3(M / 64, DMODEL / 64), dim3(256), 0, stream,
                       x, wq, (void*)xq, M, DMODEL, DMODEL, dflag_x, 2, 2);
    hipLaunchKernelGGL((gemm_bt_kernel<true>), dim3(M / 64, KVD / 64), dim3(256), 0, stream,
                       x, wk, (void*)xk, M, KVD, DMODEL, dflag_x, 2, 2);
    hipLaunchKernelGGL((gemm_bt_kernel<true>), dim3(M / 64, KVD / 64), dim3(256), 0, stream,
                       x, wv, (void*)xv, M, KVD, DMODEL, dflag_x, 2, 2);

    int npq = M * NHQ * (HD_DIM / 2);    // 4,194,304
    int npk = M * NKV_H * (HD_DIM / 2);  // 2,097,152
    hipLaunchKernelGGL(rope_kernel, dim3(npq / 256), dim3(256), 0, stream,
                       xq, fc, fs, dflag_fc, NHQ, npq);
    hipLaunchKernelGGL(rope_kernel, dim3(npk / 256), dim3(256), 0, stream,
                       xk, fc, fs, dflag_fc, NKV_H, npk);

    hipLaunchKernelGGL(attn_kernel, dim3(BATCH * NHQ * (S_LEN / 8)), dim3(256), 0, stream,
                       xq, xk, xv, mnorm, att);

    // Final GEMM: A = att (bf16), B = wo (sniffed dtype), C = d_out (FLOAT32).
    hipLaunchKernelGGL((gemm_bt_kernel<false>), dim3(M / 64, DMODEL / 64), dim3(256), 0, stream,
                       att, wo, d_out, M, DMODEL, DMODEL, dflag_x, 1, 2);
}

// Round 5
// 1761.134 us; speedup vs baseline: 1.9932x; 1.9932x over previous
//
#include <hip/hip_runtime.h>
#include <hip/hip_bf16.h>
#include <cstdint>
#include <cstddef>

#define S_LEN   2048
#define NHQ     16
#define NKV_H   8
#define HD_DIM  128
#define DMODEL  2048
#define BATCH   2
#define KVD     (NKV_H * HD_DIM)   // 1024

typedef float f32x4  __attribute__((ext_vector_type(4)));
typedef __bf16 bf16x8 __attribute__((ext_vector_type(8)));

// ---------------------------------------------------------------------------
// Dtype sniff for x: bf16 (flag=1) or f32 (flag=0)? Reads first 1024 dwords.
// ---------------------------------------------------------------------------
__global__ void sniff_x_kernel(const unsigned* __restrict__ x,
                               int* __restrict__ flag) {
    __shared__ int cnt;
    if (threadIdx.x == 0) cnt = 0;
    __syncthreads();
    int c = 0;
    for (int j = threadIdx.x; j < 1024; j += 256) {
        unsigned hw = x[j] & 0xFFFFu;
        unsigned e  = (hw >> 7) & 0xFF;
        if (hw == 0u || (e >= 118 && e <= 132)) c++;
    }
    atomicAdd(&cnt, c);
    __syncthreads();
    if (threadIdx.x == 0) *flag = (cnt > 512) ? 1 : 0;
}

__global__ void sniff_fc_kernel(const unsigned* __restrict__ fc,
                                int* __restrict__ flag) {
    if (threadIdx.x == 0) *flag = (fc[0] == 0x3F803F80u) ? 1 : 0;
}

// ---------------------------------------------------------------------------
// Mask normalization with layout sniffing (u8 / i32 / f32 / bf16).
// ---------------------------------------------------------------------------
__global__ void mask_norm_kernel(const unsigned char* __restrict__ mraw,
                                 unsigned char* __restrict__ mout, int n) {
    __shared__ int f_bf16, f_f32, f_u8;
    if (threadIdx.x == 0) { f_bf16 = 0; f_f32 = 0; f_u8 = 0; }
    __syncthreads();
    const unsigned* dw = (const unsigned*)mraw;
    int ndw = n / 4;
    for (int j = threadIdx.x; j < ndw; j += blockDim.x) {
        unsigned v = dw[j];
        if (v == 0x00003F80u || v == 0x3F803F80u) f_bf16 = 1;
        else if (v == 0x3F800000u) f_f32 = 1;
        else if (v & 0xFFFFFFFEu) f_u8 = 1;
    }
    __syncthreads();
    int layout;              // 0=u8 1=i32 2=f32 3=bf16
    if (f_bf16) layout = 3;
    else if (f_f32) layout = 2;
    else if (f_u8) layout = 0;
    else layout = 1;
    for (int i = threadIdx.x; i < n; i += blockDim.x) {
        unsigned v;
        if (layout == 0)      v = mraw[i];
        else if (layout == 3) v = ((const unsigned short*)mraw)[i];
        else                  v = ((const unsigned*)mraw)[i];
        mout[i] = v ? 1u : 0u;
    }
}

// ---------------------------------------------------------------------------
// Load 8 contiguous elements as f32 from either a bf16 or f32 buffer.
// ---------------------------------------------------------------------------
__device__ __forceinline__ void load8_f32(const void* base, size_t off,
                                          int is_bf16, float v[8]) {
    if (is_bf16) {
        uint4 u = *reinterpret_cast<const uint4*>((const __hip_bfloat16*)base + off);
        unsigned w[4] = {u.x, u.y, u.z, u.w};
#pragma unroll
        for (int i = 0; i < 4; ++i) {
            v[2 * i]     = __uint_as_float(w[i] << 16);
            v[2 * i + 1] = __uint_as_float(w[i] & 0xFFFF0000u);
        }
    } else {
        const float4* f = reinterpret_cast<const float4*>((const float*)base + off);
        float4 a = f[0], b = f[1];
        v[0] = a.x; v[1] = a.y; v[2] = a.z; v[3] = a.w;
        v[4] = b.x; v[5] = b.y; v[6] = b.z; v[7] = b.w;
    }
}

// ---------------------------------------------------------------------------
// Tiled GEMM, C[M,N] = A[M,K] @ Bw[N,K]^T, fp32 accumulate (VALU version,
// known-good from round 4; MFMA upgrade is next round's change).
// ---------------------------------------------------------------------------
template <bool OUT_BF16>
__global__ __launch_bounds__(256)
void gemm_bt_kernel(const void* __restrict__ A, const void* __restrict__ Bw,
                    void* __restrict__ Cv, int M, int N, int K,
                    const int* __restrict__ dflag, int a_mode, int b_mode) {
    __shared__ float As[32][68];
    __shared__ float Bs[32][68];
    const int abf = (a_mode == 2) ? *dflag : a_mode;
    const int bbf = (b_mode == 2) ? *dflag : b_mode;
    const int t  = threadIdx.x;
    const int tx = t & 15, ty = t >> 4;
    const int m0 = blockIdx.x * 64, n0 = blockIdx.y * 64;
    const int row = t >> 2;
    const int kc  = (t & 3) * 8;
    float acc[4][4] = {};

    for (int k0 = 0; k0 < K; k0 += 32) {
        float va[8], vb[8];
        load8_f32(A,  (size_t)(m0 + row) * K + (k0 + kc), abf, va);
        load8_f32(Bw, (size_t)(n0 + row) * K + (k0 + kc), bbf, vb);
#pragma unroll
        for (int j = 0; j < 8; ++j) As[kc + j][row] = va[j];
#pragma unroll
        for (int j = 0; j < 8; ++j) Bs[kc + j][row] = vb[j];
        __syncthreads();
#pragma unroll
        for (int kk = 0; kk < 32; ++kk) {
            float4 a = *reinterpret_cast<const float4*>(&As[kk][ty * 4]);
            float4 b = *reinterpret_cast<const float4*>(&Bs[kk][tx * 4]);
            float av[4] = {a.x, a.y, a.z, a.w};
            float bv[4] = {b.x, b.y, b.z, b.w};
#pragma unroll
            for (int i = 0; i < 4; ++i)
#pragma unroll
                for (int j = 0; j < 4; ++j) acc[i][j] += av[i] * bv[j];
        }
        __syncthreads();
    }
#pragma unroll
    for (int i = 0; i < 4; ++i) {
        int m = m0 + ty * 4 + i;
#pragma unroll
        for (int j = 0; j < 4; ++j) {
            int n = n0 + tx * 4 + j;
            if constexpr (OUT_BF16)
                ((__hip_bfloat16*)Cv)[(size_t)m * N + n] = __float2bfloat16(acc[i][j]);
            else
                ((float*)Cv)[(size_t)m * N + n] = acc[i][j];
        }
    }
}

// ---------------------------------------------------------------------------
// RoPE in-place on bf16 [B*S, nheads*128]; pair i rotates (2i, 2i+1).
// ---------------------------------------------------------------------------
__global__ void rope_kernel(__hip_bfloat16* __restrict__ xqk,
                            const void* __restrict__ cosv,
                            const void* __restrict__ sinv,
                            const int* __restrict__ dflag_fc,
                            int nheads, int npairs) {
    int idx = blockIdx.x * blockDim.x + threadIdx.x;
    if (idx >= npairs) return;
    int i  = idx & 63;
    int h  = (idx >> 6) % nheads;
    int bs = idx / (64 * nheads);
    int s  = bs & (S_LEN - 1);
    float c, sn;
    if (*dflag_fc) {
        c  = __bfloat162float(((const __hip_bfloat16*)cosv)[s * 64 + i]);
        sn = __bfloat162float(((const __hip_bfloat16*)sinv)[s * 64 + i]);
    } else {
        c  = ((const float*)cosv)[s * 64 + i];
        sn = ((const float*)sinv)[s * 64 + i];
    }
    unsigned* p = (unsigned*)(xqk + (size_t)bs * (nheads * HD_DIM) + h * HD_DIM) + i;
    unsigned u = *p;
    float xr = __uint_as_float(u << 16);
    float xi = __uint_as_float(u & 0xFFFF0000u);
    float o0 = xr * c - xi * sn;
    float o1 = xr * sn + xi * c;
    union { __hip_bfloat16 h2[2]; unsigned u32; } out;
    out.h2[0] = __float2bfloat16(o0);
    out.h2[1] = __float2bfloat16(o1);
    *p = out.u32;
}

// ---------------------------------------------------------------------------
// V transpose: xv [B*S][KVD] -> vt [(b*NKV+kv)*128 + d][S]. 32x32 LDS tiles.
// ---------------------------------------------------------------------------
__global__ __launch_bounds__(256)
void transpose_v_kernel(const __hip_bfloat16* __restrict__ xv,
                        __hip_bfloat16* __restrict__ vt) {
    __shared__ unsigned short T[32][36];
    const int t  = threadIdx.x;
    const int s0 = blockIdx.x * 32;      // 64 s-tiles
    const int d0 = blockIdx.y * 32;      // 4  d-tiles
    const int z  = blockIdx.z;           // b*NKV + kv (16)
    const int b  = z >> 3;
    const int kv = z & 7;
    {
        int sr = t >> 3, dc = (t & 7) * 4;
        const unsigned short* p = (const unsigned short*)xv
            + (size_t)(b * S_LEN + s0 + sr) * KVD + kv * 128 + d0 + dc;
        uint2 v = *reinterpret_cast<const uint2*>(p);
        T[sr][dc + 0] = (unsigned short)(v.x & 0xFFFFu);
        T[sr][dc + 1] = (unsigned short)(v.x >> 16);
        T[sr][dc + 2] = (unsigned short)(v.y & 0xFFFFu);
        T[sr][dc + 3] = (unsigned short)(v.y >> 16);
    }
    __syncthreads();
    {
        int dr = t >> 3, sc = (t & 7) * 4;
        unsigned w0 = (unsigned)T[sc + 0][dr] | ((unsigned)T[sc + 1][dr] << 16);
        unsigned w1 = (unsigned)T[sc + 2][dr] | ((unsigned)T[sc + 3][dr] << 16);
        unsigned short* q = (unsigned short*)vt
            + ((size_t)z * 128 + d0 + dr) * S_LEN + s0 + sc;
        uint2 v; v.x = w0; v.y = w1;
        *reinterpret_cast<uint2*>(q) = v;
    }
}

// ---------------------------------------------------------------------------
// MFMA flash attention. Block = 4 waves = 64 q rows of one (b,h).
// Key tiles of 64. mfma_f32_16x16x32_bf16:
//   A/B frag:  elem j of lane -> [m or n = lane&15][k = (lane>>4)*8 + j]
//   C/D:       lane reg r      -> [row m = (lane>>4)*4 + r][col n = lane&15]
// QK^T: A=Q rows, B=K rows (B^T pattern, both row-major in LDS).
// PV:   A=P (LDS round-trip from C-layout), B=V^T (pre-transposed global vt).
// att aliases xq: block writes exactly the (rows, head-cols) it alone reads.
// ---------------------------------------------------------------------------
__global__ __launch_bounds__(256)
void attn_mfma_kernel(const __hip_bfloat16* xq,
                      const __hip_bfloat16* __restrict__ xk,
                      const __hip_bfloat16* __restrict__ vt_g,
                      const unsigned char* __restrict__ msk,
                      __hip_bfloat16* att) {
    __shared__ __bf16 Qs[64][136];     // 17408 B (pitch 272B: 16B-aligned, bank-spread)
    __shared__ __bf16 Ks[64][136];     // 17408 B
    __shared__ __bf16 Vt[128][72];     //  18432 B (pitch 144B)
    __shared__ __bf16 Ps[4][16][72];   //  9216 B (per-wave P buffer)

    const int t    = threadIdx.x;
    const int w    = t >> 6;
    const int lane = t & 63;
    const int quad = lane >> 4;
    const int l16  = lane & 15;

    const int bid = blockIdx.x;
    const int qt  = bid & 31;            // 32 q-tiles of 64 rows
    const int h   = (bid >> 5) & (NHQ - 1);
    const int b   = bid >> 9;
    const int kvh = h >> 1;              // GQA n_rep = 2
    const int q0  = qt * 64;

    // ---- stage Q (64 rows x 128) ----
#pragma unroll
    for (int i = 0; i < 4; ++i) {
        int p = t + i * 256;
        int r = p >> 4, c = p & 15;
        *reinterpret_cast<uint4*>(&Qs[r][c * 8]) =
            *reinterpret_cast<const uint4*>((const unsigned short*)xq
                + (size_t)(b * S_LEN + q0 + r) * DMODEL + h * 128 + c * 8);
    }

    float m_r[4], l_r[4];
    f32x4 o[8];
#pragma unroll
    for (int r = 0; r < 4; ++r) { m_r[r] = -INFINITY; l_r[r] = 0.f; }
#pragma unroll
    for (int d0 = 0; d0 < 8; ++d0) o[d0] = (f32x4){0.f, 0.f, 0.f, 0.f};

    const float scale = 0.08838834764831845f;  // 1/sqrt(128)

    for (int k0 = 0; k0 < S_LEN; k0 += 64) {
        __syncthreads();   // previous tile's LDS reads complete (also covers Q staging)
        // ---- stage K tile (64 keys x 128) ----
#pragma unroll
        for (int i = 0; i < 4; ++i) {
            int p = t + i * 256;
            int r = p >> 4, c = p & 15;
            *reinterpret_cast<uint4*>(&Ks[r][c * 8]) =
                *reinterpret_cast<const uint4*>((const unsigned short*)xk
                    + (size_t)(b * S_LEN + k0 + r) * KVD + kvh * 128 + c * 8);
        }
        // ---- stage V^T tile (128 d x 64 keys) from pre-transposed vt ----
#pragma unroll
        for (int i = 0; i < 4; ++i) {
            int p = t + i * 256;
            int d = p >> 3, c = p & 7;
            *reinterpret_cast<uint4*>(&Vt[d][c * 8]) =
                *reinterpret_cast<const uint4*>((const unsigned short*)vt_g
                    + ((size_t)(b * NKV_H + kvh) * 128 + d) * S_LEN + k0 + c * 8);
        }
        int mk[4];
#pragma unroll
        for (int n0 = 0; n0 < 4; ++n0)
            mk[n0] = msk[b * S_LEN + k0 + n0 * 16 + l16];
        __syncthreads();

        // ---- QK^T: 16 q-rows (this wave) x 64 keys ----
        f32x4 sc4[4];
#pragma unroll
        for (int n0 = 0; n0 < 4; ++n0) sc4[n0] = (f32x4){0.f, 0.f, 0.f, 0.f};
#pragma unroll
        for (int ks = 0; ks < 4; ++ks) {
            int khd = ks * 32 + quad * 8;
            bf16x8 af = *reinterpret_cast<const bf16x8*>(&Qs[w * 16 + l16][khd]);
#pragma unroll
            for (int n0 = 0; n0 < 4; ++n0) {
                bf16x8 bf = *reinterpret_cast<const bf16x8*>(&Ks[n0 * 16 + l16][khd]);
                sc4[n0] = __builtin_amdgcn_mfma_f32_16x16x32_bf16(af, bf, sc4[n0], 0, 0, 0);
            }
        }

        // ---- scale + mask + online softmax (rows = quad*4+reg, cols = l16) ----
#pragma unroll
        for (int n0 = 0; n0 < 4; ++n0)
#pragma unroll
            for (int r = 0; r < 4; ++r) {
                float v = sc4[n0][r] * scale;
                sc4[n0][r] = mk[n0] ? -INFINITY : v;
            }
        float alpha[4];
#pragma unroll
        for (int r = 0; r < 4; ++r) {
            float rmax = fmaxf(fmaxf(sc4[0][r], sc4[1][r]), fmaxf(sc4[2][r], sc4[3][r]));
#pragma unroll
            for (int m = 1; m < 16; m <<= 1)
                rmax = fmaxf(rmax, __shfl_xor(rmax, m, 64));
            float mn = fmaxf(m_r[r], rmax);
            alpha[r] = __expf(m_r[r] - mn);   // 0 on first tile (m_old=-inf, mn finite)
            m_r[r] = mn;
            float rs = 0.f;
#pragma unroll
            for (int n0 = 0; n0 < 4; ++n0) {
                float p = __expf(sc4[n0][r] - mn);
                sc4[n0][r] = p;
                rs += p;
            }
#pragma unroll
            for (int m = 1; m < 16; m <<= 1)
                rs += __shfl_xor(rs, m, 64);
            l_r[r] = l_r[r] * alpha[r] + rs;
        }
#pragma unroll
        for (int d0 = 0; d0 < 8; ++d0)
#pragma unroll
            for (int r = 0; r < 4; ++r) o[d0][r] *= alpha[r];

        // ---- P: C-layout regs -> A-layout via per-wave LDS ----
#pragma unroll
        for (int n0 = 0; n0 < 4; ++n0)
#pragma unroll
            for (int r = 0; r < 4; ++r)
                Ps[w][quad * 4 + r][n0 * 16 + l16] = (__bf16)sc4[n0][r];

        // ---- PV: O[16 q][128 d] += P[16][64] * V[64][128] ----
#pragma unroll
        for (int kk = 0; kk < 64; kk += 32) {
            bf16x8 af = *reinterpret_cast<const bf16x8*>(&Ps[w][l16][kk + quad * 8]);
#pragma unroll
            for (int d0 = 0; d0 < 8; ++d0) {
                bf16x8 bf = *reinterpret_cast<const bf16x8*>(&Vt[d0 * 16 + l16][kk + quad * 8]);
                o[d0] = __builtin_amdgcn_mfma_f32_16x16x32_bf16(af, bf, o[d0], 0, 0, 0);
            }
        }
    }

    // ---- epilogue: normalize, write (rows = quad*4+reg of this wave) ----
    float inv[4];
#pragma unroll
    for (int r = 0; r < 4; ++r) inv[r] = 1.f / l_r[r];
#pragma unroll
    for (int d0 = 0; d0 < 8; ++d0)
#pragma unroll
        for (int r = 0; r < 4; ++r) {
            size_t row = (size_t)(b * S_LEN + q0 + w * 16 + quad * 4 + r);
            att[row * DMODEL + h * 128 + d0 * 16 + l16] =
                __float2bfloat16(o[d0][r] * inv[r]);
        }
}

// ---------------------------------------------------------------------------
extern "C" void kernel_launch(void* const* d_in, const int* in_sizes, int n_in,
                              void* d_out, int out_size, void* d_ws, size_t ws_size,
                              hipStream_t stream) {
    const void* x  = d_in[0];
    const void* wq = d_in[1];
    const void* wk = d_in[2];
    const void* wv = d_in[3];
    const void* wo = d_in[4];
    const void* fc = d_in[5];
    const void* fs = d_in[6];
    const unsigned char* mraw = (const unsigned char*)d_in[7];

    const int M = BATCH * S_LEN;                                 // 4096
    // ws layout (proven, 32 MB + 8 KB): control block first, then bf16 tensors.
    char* wsb = (char*)d_ws;
    int* dflag_x  = (int*)wsb;                                   // @0
    int* dflag_fc = (int*)(wsb + 64);                            // @64
    unsigned char* mnorm = (unsigned char*)(wsb + 128);          // @128, 4 KB
    __hip_bfloat16* xq = (__hip_bfloat16*)(wsb + 8192);          // 16 MB (att aliases)
    __hip_bfloat16* xk = xq + (size_t)M * DMODEL;                // 8 MB
    __hip_bfloat16* xv = xk + (size_t)M * KVD;                   // 8 MB
    __hip_bfloat16* att = xq;                                    // alias (safe, see attn)
    // V^T scratch lives in d_out (32 MB f32): free until the final GEMM,
    // which is ordered after attention on the same stream.
    __hip_bfloat16* vt = (__hip_bfloat16*)d_out;                 // 8 MB of 32 MB

    hipLaunchKernelGGL(sniff_x_kernel, dim3(1), dim3(256), 0, stream,
                       (const unsigned*)x, dflag_x);
    hipLaunchKernelGGL(sniff_fc_kernel, dim3(1), dim3(64), 0, stream,
                       (const unsigned*)fc, dflag_fc);
    hipLaunchKernelGGL(mask_norm_kernel, dim3(1), dim3(256), 0, stream,
                       mraw, mnorm, BATCH * S_LEN);

    hipLaunchKernelGGL((gemm_bt_kernel<true>), dim3(M / 64, DMODEL / 64), dim3(256), 0, stream,
                       x, wq, (void*)xq, M, DMODEL, DMODEL, dflag_x, 2, 2);
    hipLaunchKernelGGL((gemm_bt_kernel<true>), dim3(M / 64, KVD / 64), dim3(256), 0, stream,
                       x, wk, (void*)xk, M, KVD, DMODEL, dflag_x, 2, 2);
    hipLaunchKernelGGL((gemm_bt_kernel<true>), dim3(M / 64, KVD / 64), dim3(256), 0, stream,
                       x, wv, (void*)xv, M, KVD, DMODEL, dflag_x, 2, 2);

    int npq = M * NHQ * (HD_DIM / 2);    // 4,194,304
    int npk = M * NKV_H * (HD_DIM / 2);  // 2,097,152
    hipLaunchKernelGGL(rope_kernel, dim3(npq / 256), dim3(256), 0, stream,
                       xq, fc, fs, dflag_fc, NHQ, npq);
    hipLaunchKernelGGL(rope_kernel, dim3(npk / 256), dim3(256), 0, stream,
                       xk, fc, fs, dflag_fc, NKV_H, npk);

    hipLaunchKernelGGL(transpose_v_kernel, dim3(S_LEN / 32, HD_DIM / 32, BATCH * NKV_H),
                       dim3(256), 0, stream, xv, vt);

    hipLaunchKernelGGL(attn_mfma_kernel, dim3(BATCH * NHQ * (S_LEN / 64)), dim3(256), 0, stream,
                       xq, xk, vt, mnorm, att);

    // Final GEMM: A = att (bf16), B = wo (sniffed dtype), C = d_out (f32).
    hipLaunchKernelGGL((gemm_bt_kernel<false>), dim3(M / 64, DMODEL / 64), dim3(256), 0, stream,
                       att, wo, d_out, M, DMODEL, DMODEL, dflag_x, 1, 2);
}

// Round 6
// 849.260 us; speedup vs baseline: 4.1333x; 2.0737x over previous
//
#include <hip/hip_runtime.h>
#include <hip/hip_bf16.h>
#include <cstdint>
#include <cstddef>

#define S_LEN   2048
#define NHQ     16
#define NKV_H   8
#define HD_DIM  128
#define DMODEL  2048
#define BATCH   2
#define KVD     (NKV_H * HD_DIM)   // 1024

typedef float f32x4  __attribute__((ext_vector_type(4)));
typedef __bf16 bf16x8 __attribute__((ext_vector_type(8)));

// ---------------------------------------------------------------------------
// Dtype sniff for x: bf16 (flag=1) or f32 (flag=0)? Reads first 1024 dwords.
// ---------------------------------------------------------------------------
__global__ void sniff_x_kernel(const unsigned* __restrict__ x,
                               int* __restrict__ flag) {
    __shared__ int cnt;
    if (threadIdx.x == 0) cnt = 0;
    __syncthreads();
    int c = 0;
    for (int j = threadIdx.x; j < 1024; j += 256) {
        unsigned hw = x[j] & 0xFFFFu;
        unsigned e  = (hw >> 7) & 0xFF;
        if (hw == 0u || (e >= 118 && e <= 132)) c++;
    }
    atomicAdd(&cnt, c);
    __syncthreads();
    if (threadIdx.x == 0) *flag = (cnt > 512) ? 1 : 0;
}

__global__ void sniff_fc_kernel(const unsigned* __restrict__ fc,
                                int* __restrict__ flag) {
    if (threadIdx.x == 0) *flag = (fc[0] == 0x3F803F80u) ? 1 : 0;
}

// ---------------------------------------------------------------------------
// Mask normalization with layout sniffing (u8 / i32 / f32 / bf16).
// ---------------------------------------------------------------------------
__global__ void mask_norm_kernel(const unsigned char* __restrict__ mraw,
                                 unsigned char* __restrict__ mout, int n) {
    __shared__ int f_bf16, f_f32, f_u8;
    if (threadIdx.x == 0) { f_bf16 = 0; f_f32 = 0; f_u8 = 0; }
    __syncthreads();
    const unsigned* dw = (const unsigned*)mraw;
    int ndw = n / 4;
    for (int j = threadIdx.x; j < ndw; j += blockDim.x) {
        unsigned v = dw[j];
        if (v == 0x00003F80u || v == 0x3F803F80u) f_bf16 = 1;
        else if (v == 0x3F800000u) f_f32 = 1;
        else if (v & 0xFFFFFFFEu) f_u8 = 1;
    }
    __syncthreads();
    int layout;              // 0=u8 1=i32 2=f32 3=bf16
    if (f_bf16) layout = 3;
    else if (f_f32) layout = 2;
    else if (f_u8) layout = 0;
    else layout = 1;
    for (int i = threadIdx.x; i < n; i += blockDim.x) {
        unsigned v;
        if (layout == 0)      v = mraw[i];
        else if (layout == 3) v = ((const unsigned short*)mraw)[i];
        else                  v = ((const unsigned*)mraw)[i];
        mout[i] = v ? 1u : 0u;
    }
}

// ---------------------------------------------------------------------------
// Stage one 128x64 tile (rows row_base.., k0..k0+63) into LDS as bf16,
// converting from f32 if needed. 256 threads, 8 threads/row, 4 passes.
// ---------------------------------------------------------------------------
__device__ __forceinline__ void stage_tile_bf16(const void* src, int is_bf16,
                                                size_t row_base, int K, int k0,
                                                __bf16 (*dst)[72], int t) {
    const int r0 = t >> 3;
    const int c  = (t & 7) * 8;
#pragma unroll
    for (int p = 0; p < 4; ++p) {
        int r = r0 + p * 32;
        bf16x8 v;
        if (is_bf16) {
            v = *reinterpret_cast<const bf16x8*>(
                (const __bf16*)src + (row_base + r) * (size_t)K + k0 + c);
        } else {
            const float* f = (const float*)src + (row_base + r) * (size_t)K + k0 + c;
            float4 f0 = *reinterpret_cast<const float4*>(f);
            float4 f1 = *reinterpret_cast<const float4*>(f + 4);
            v[0] = (__bf16)f0.x; v[1] = (__bf16)f0.y;
            v[2] = (__bf16)f0.z; v[3] = (__bf16)f0.w;
            v[4] = (__bf16)f1.x; v[5] = (__bf16)f1.y;
            v[6] = (__bf16)f1.z; v[7] = (__bf16)f1.w;
        }
        *reinterpret_cast<bf16x8*>(&dst[r][c]) = v;
    }
}

// ---------------------------------------------------------------------------
// MFMA GEMM: C[M,N] = A[M,K] @ Bw[N,K]^T, fp32 accumulate (AGPR).
// 128x128 block tile, BK=64, 4 waves in 2x2, each wave 64x64 = 4x4 MFMA tiles.
// mfma_f32_16x16x32_bf16 layouts (m89/m91-verified):
//   A/B frag: elem j of lane -> [m|n = lane&15][k = (lane>>4)*8 + j]
//   C/D:      lane reg r     -> [row = (lane>>4)*4 + r][col = lane&15]
// a_mode/b_mode: 0 = f32, 1 = bf16, 2 = per *dflag.
// ---------------------------------------------------------------------------
template <bool OUT_BF16>
__global__ __launch_bounds__(256)
void gemm_bt_mfma(const void* __restrict__ A, const void* __restrict__ Bw,
                  void* __restrict__ Cv, int M, int N, int K,
                  const int* __restrict__ dflag, int a_mode, int b_mode) {
    __shared__ __bf16 As[128][72];   // 18432 B, pitch 144 B (4r mod 32 bank spread)
    __shared__ __bf16 Bs[128][72];   // 18432 B
    const int abf = (a_mode == 2) ? *dflag : a_mode;
    const int bbf = (b_mode == 2) ? *dflag : b_mode;

    const int t    = threadIdx.x;
    const int w    = t >> 6;
    const int lane = t & 63;
    const int quad = lane >> 4;
    const int l16  = lane & 15;
    const int wm   = (w >> 1) * 64;
    const int wn   = (w & 1) * 64;
    const int m0   = blockIdx.x * 128;
    const int n0   = blockIdx.y * 128;

    f32x4 acc[4][4];
#pragma unroll
    for (int i = 0; i < 4; ++i)
#pragma unroll
        for (int j = 0; j < 4; ++j) acc[i][j] = (f32x4){0.f, 0.f, 0.f, 0.f};

    for (int k0 = 0; k0 < K; k0 += 64) {
        __syncthreads();   // previous iteration's ds_reads complete
        stage_tile_bf16(A,  abf, (size_t)m0, K, k0, As, t);
        stage_tile_bf16(Bw, bbf, (size_t)n0, K, k0, Bs, t);
        __syncthreads();
#pragma unroll
        for (int ks = 0; ks < 2; ++ks) {
            const int khd = ks * 32 + quad * 8;
            bf16x8 af[4], bf[4];
#pragma unroll
            for (int i = 0; i < 4; ++i)
                af[i] = *reinterpret_cast<const bf16x8*>(&As[wm + i * 16 + l16][khd]);
#pragma unroll
            for (int j = 0; j < 4; ++j)
                bf[j] = *reinterpret_cast<const bf16x8*>(&Bs[wn + j * 16 + l16][khd]);
#pragma unroll
            for (int i = 0; i < 4; ++i)
#pragma unroll
                for (int j = 0; j < 4; ++j)
                    acc[i][j] = __builtin_amdgcn_mfma_f32_16x16x32_bf16(
                        af[i], bf[j], acc[i][j], 0, 0, 0);
        }
    }
    // epilogue: C rows = m0+wm+i*16+quad*4+r, cols = n0+wn+j*16+l16
#pragma unroll
    for (int i = 0; i < 4; ++i)
#pragma unroll
        for (int r = 0; r < 4; ++r) {
            size_t m = (size_t)(m0 + wm + i * 16 + quad * 4 + r);
#pragma unroll
            for (int j = 0; j < 4; ++j) {
                int n = n0 + wn + j * 16 + l16;
                if constexpr (OUT_BF16)
                    ((__hip_bfloat16*)Cv)[m * N + n] = __float2bfloat16(acc[i][j][r]);
                else
                    ((float*)Cv)[m * N + n] = acc[i][j][r];
            }
        }
}

// ---------------------------------------------------------------------------
// RoPE in-place on bf16 [B*S, nheads*128]; pair i rotates (2i, 2i+1).
// ---------------------------------------------------------------------------
__global__ void rope_kernel(__hip_bfloat16* __restrict__ xqk,
                            const void* __restrict__ cosv,
                            const void* __restrict__ sinv,
                            const int* __restrict__ dflag_fc,
                            int nheads, int npairs) {
    int idx = blockIdx.x * blockDim.x + threadIdx.x;
    if (idx >= npairs) return;
    int i  = idx & 63;
    int h  = (idx >> 6) % nheads;
    int bs = idx / (64 * nheads);
    int s  = bs & (S_LEN - 1);
    float c, sn;
    if (*dflag_fc) {
        c  = __bfloat162float(((const __hip_bfloat16*)cosv)[s * 64 + i]);
        sn = __bfloat162float(((const __hip_bfloat16*)sinv)[s * 64 + i]);
    } else {
        c  = ((const float*)cosv)[s * 64 + i];
        sn = ((const float*)sinv)[s * 64 + i];
    }
    unsigned* p = (unsigned*)(xqk + (size_t)bs * (nheads * HD_DIM) + h * HD_DIM) + i;
    unsigned u = *p;
    float xr = __uint_as_float(u << 16);
    float xi = __uint_as_float(u & 0xFFFF0000u);
    float o0 = xr * c - xi * sn;
    float o1 = xr * sn + xi * c;
    union { __hip_bfloat16 h2[2]; unsigned u32; } out;
    out.h2[0] = __float2bfloat16(o0);
    out.h2[1] = __float2bfloat16(o1);
    *p = out.u32;
}

// ---------------------------------------------------------------------------
// V transpose: xv [B*S][KVD] -> vt [(b*NKV+kv)*128 + d][S]. 32x32 LDS tiles.
// ---------------------------------------------------------------------------
__global__ __launch_bounds__(256)
void transpose_v_kernel(const __hip_bfloat16* __restrict__ xv,
                        __hip_bfloat16* __restrict__ vt) {
    __shared__ unsigned short T[32][36];
    const int t  = threadIdx.x;
    const int s0 = blockIdx.x * 32;
    const int d0 = blockIdx.y * 32;
    const int z  = blockIdx.z;           // b*NKV + kv
    const int b  = z >> 3;
    const int kv = z & 7;
    {
        int sr = t >> 3, dc = (t & 7) * 4;
        const unsigned short* p = (const unsigned short*)xv
            + (size_t)(b * S_LEN + s0 + sr) * KVD + kv * 128 + d0 + dc;
        uint2 v = *reinterpret_cast<const uint2*>(p);
        T[sr][dc + 0] = (unsigned short)(v.x & 0xFFFFu);
        T[sr][dc + 1] = (unsigned short)(v.x >> 16);
        T[sr][dc + 2] = (unsigned short)(v.y & 0xFFFFu);
        T[sr][dc + 3] = (unsigned short)(v.y >> 16);
    }
    __syncthreads();
    {
        int dr = t >> 3, sc = (t & 7) * 4;
        unsigned w0 = (unsigned)T[sc + 0][dr] | ((unsigned)T[sc + 1][dr] << 16);
        unsigned w1 = (unsigned)T[sc + 2][dr] | ((unsigned)T[sc + 3][dr] << 16);
        unsigned short* q = (unsigned short*)vt
            + ((size_t)z * 128 + d0 + dr) * S_LEN + s0 + sc;
        uint2 v; v.x = w0; v.y = w1;
        *reinterpret_cast<uint2*>(q) = v;
    }
}

// ---------------------------------------------------------------------------
// MFMA flash attention (round-5 proven). Block = 4 waves = 64 q rows of (b,h).
// ---------------------------------------------------------------------------
__global__ __launch_bounds__(256)
void attn_mfma_kernel(const __hip_bfloat16* xq,
                      const __hip_bfloat16* __restrict__ xk,
                      const __hip_bfloat16* __restrict__ vt_g,
                      const unsigned char* __restrict__ msk,
                      __hip_bfloat16* att) {
    __shared__ __bf16 Qs[64][136];
    __shared__ __bf16 Ks[64][136];
    __shared__ __bf16 Vt[128][72];
    __shared__ __bf16 Ps[4][16][72];

    const int t    = threadIdx.x;
    const int w    = t >> 6;
    const int lane = t & 63;
    const int quad = lane >> 4;
    const int l16  = lane & 15;

    const int bid = blockIdx.x;
    const int qt  = bid & 31;
    const int h   = (bid >> 5) & (NHQ - 1);
    const int b   = bid >> 9;
    const int kvh = h >> 1;
    const int q0  = qt * 64;

#pragma unroll
    for (int i = 0; i < 4; ++i) {
        int p = t + i * 256;
        int r = p >> 4, c = p & 15;
        *reinterpret_cast<uint4*>(&Qs[r][c * 8]) =
            *reinterpret_cast<const uint4*>((const unsigned short*)xq
                + (size_t)(b * S_LEN + q0 + r) * DMODEL + h * 128 + c * 8);
    }

    float m_r[4], l_r[4];
    f32x4 o[8];
#pragma unroll
    for (int r = 0; r < 4; ++r) { m_r[r] = -INFINITY; l_r[r] = 0.f; }
#pragma unroll
    for (int d0 = 0; d0 < 8; ++d0) o[d0] = (f32x4){0.f, 0.f, 0.f, 0.f};

    const float scale = 0.08838834764831845f;  // 1/sqrt(128)

    for (int k0 = 0; k0 < S_LEN; k0 += 64) {
        __syncthreads();
#pragma unroll
        for (int i = 0; i < 4; ++i) {
            int p = t + i * 256;
            int r = p >> 4, c = p & 15;
            *reinterpret_cast<uint4*>(&Ks[r][c * 8]) =
                *reinterpret_cast<const uint4*>((const unsigned short*)xk
                    + (size_t)(b * S_LEN + k0 + r) * KVD + kvh * 128 + c * 8);
        }
#pragma unroll
        for (int i = 0; i < 4; ++i) {
            int p = t + i * 256;
            int d = p >> 3, c = p & 7;
            *reinterpret_cast<uint4*>(&Vt[d][c * 8]) =
                *reinterpret_cast<const uint4*>((const unsigned short*)vt_g
                    + ((size_t)(b * NKV_H + kvh) * 128 + d) * S_LEN + k0 + c * 8);
        }
        int mk[4];
#pragma unroll
        for (int n0 = 0; n0 < 4; ++n0)
            mk[n0] = msk[b * S_LEN + k0 + n0 * 16 + l16];
        __syncthreads();

        f32x4 sc4[4];
#pragma unroll
        for (int n0 = 0; n0 < 4; ++n0) sc4[n0] = (f32x4){0.f, 0.f, 0.f, 0.f};
#pragma unroll
        for (int ks = 0; ks < 4; ++ks) {
            int khd = ks * 32 + quad * 8;
            bf16x8 af = *reinterpret_cast<const bf16x8*>(&Qs[w * 16 + l16][khd]);
#pragma unroll
            for (int n0 = 0; n0 < 4; ++n0) {
                bf16x8 bf = *reinterpret_cast<const bf16x8*>(&Ks[n0 * 16 + l16][khd]);
                sc4[n0] = __builtin_amdgcn_mfma_f32_16x16x32_bf16(af, bf, sc4[n0], 0, 0, 0);
            }
        }

#pragma unroll
        for (int n0 = 0; n0 < 4; ++n0)
#pragma unroll
            for (int r = 0; r < 4; ++r) {
                float v = sc4[n0][r] * scale;
                sc4[n0][r] = mk[n0] ? -INFINITY : v;
            }
        float alpha[4];
#pragma unroll
        for (int r = 0; r < 4; ++r) {
            float rmax = fmaxf(fmaxf(sc4[0][r], sc4[1][r]), fmaxf(sc4[2][r], sc4[3][r]));
#pragma unroll
            for (int m = 1; m < 16; m <<= 1)
                rmax = fmaxf(rmax, __shfl_xor(rmax, m, 64));
            float mn = fmaxf(m_r[r], rmax);
            alpha[r] = __expf(m_r[r] - mn);
            m_r[r] = mn;
            float rs = 0.f;
#pragma unroll
            for (int n0 = 0; n0 < 4; ++n0) {
                float p = __expf(sc4[n0][r] - mn);
                sc4[n0][r] = p;
                rs += p;
            }
#pragma unroll
            for (int m = 1; m < 16; m <<= 1)
                rs += __shfl_xor(rs, m, 64);
            l_r[r] = l_r[r] * alpha[r] + rs;
        }
#pragma unroll
        for (int d0 = 0; d0 < 8; ++d0)
#pragma unroll
            for (int r = 0; r < 4; ++r) o[d0][r] *= alpha[r];

#pragma unroll
        for (int n0 = 0; n0 < 4; ++n0)
#pragma unroll
            for (int r = 0; r < 4; ++r)
                Ps[w][quad * 4 + r][n0 * 16 + l16] = (__bf16)sc4[n0][r];

#pragma unroll
        for (int kk = 0; kk < 64; kk += 32) {
            bf16x8 af = *reinterpret_cast<const bf16x8*>(&Ps[w][l16][kk + quad * 8]);
#pragma unroll
            for (int d0 = 0; d0 < 8; ++d0) {
                bf16x8 bf = *reinterpret_cast<const bf16x8*>(&Vt[d0 * 16 + l16][kk + quad * 8]);
                o[d0] = __builtin_amdgcn_mfma_f32_16x16x32_bf16(af, bf, o[d0], 0, 0, 0);
            }
        }
    }

    float inv[4];
#pragma unroll
    for (int r = 0; r < 4; ++r) inv[r] = 1.f / l_r[r];
#pragma unroll
    for (int d0 = 0; d0 < 8; ++d0)
#pragma unroll
        for (int r = 0; r < 4; ++r) {
            size_t row = (size_t)(b * S_LEN + q0 + w * 16 + quad * 4 + r);
            att[row * DMODEL + h * 128 + d0 * 16 + l16] =
                __float2bfloat16(o[d0][r] * inv[r]);
        }
}

// ---------------------------------------------------------------------------
extern "C" void kernel_launch(void* const* d_in, const int* in_sizes, int n_in,
                              void* d_out, int out_size, void* d_ws, size_t ws_size,
                              hipStream_t stream) {
    const void* x  = d_in[0];
    const void* wq = d_in[1];
    const void* wk = d_in[2];
    const void* wv = d_in[3];
    const void* wo = d_in[4];
    const void* fc = d_in[5];
    const void* fs = d_in[6];
    const unsigned char* mraw = (const unsigned char*)d_in[7];

    const int M = BATCH * S_LEN;                                 // 4096
    char* wsb = (char*)d_ws;
    int* dflag_x  = (int*)wsb;                                   // @0
    int* dflag_fc = (int*)(wsb + 64);                            // @64
    unsigned char* mnorm = (unsigned char*)(wsb + 128);          // @128, 4 KB
    __hip_bfloat16* xq = (__hip_bfloat16*)(wsb + 8192);          // 16 MB (att aliases)
    __hip_bfloat16* xk = xq + (size_t)M * DMODEL;                // 8 MB
    __hip_bfloat16* xv = xk + (size_t)M * KVD;                   // 8 MB
    __hip_bfloat16* att = xq;                                    // alias (safe)
    __hip_bfloat16* vt = (__hip_bfloat16*)d_out;                 // 8 MB of d_out's 32 MB

    hipLaunchKernelGGL(sniff_x_kernel, dim3(1), dim3(256), 0, stream,
                       (const unsigned*)x, dflag_x);
    hipLaunchKernelGGL(sniff_fc_kernel, dim3(1), dim3(64), 0, stream,
                       (const unsigned*)fc, dflag_fc);
    hipLaunchKernelGGL(mask_norm_kernel, dim3(1), dim3(256), 0, stream,
                       mraw, mnorm, BATCH * S_LEN);

    hipLaunchKernelGGL((gemm_bt_mfma<true>), dim3(M / 128, DMODEL / 128), dim3(256), 0, stream,
                       x, wq, (void*)xq, M, DMODEL, DMODEL, dflag_x, 2, 2);
    hipLaunchKernelGGL((gemm_bt_mfma<true>), dim3(M / 128, KVD / 128), dim3(256), 0, stream,
                       x, wk, (void*)xk, M, KVD, DMODEL, dflag_x, 2, 2);
    hipLaunchKernelGGL((gemm_bt_mfma<true>), dim3(M / 128, KVD / 128), dim3(256), 0, stream,
                       x, wv, (void*)xv, M, KVD, DMODEL, dflag_x, 2, 2);

    int npq = M * NHQ * (HD_DIM / 2);
    int npk = M * NKV_H * (HD_DIM / 2);
    hipLaunchKernelGGL(rope_kernel, dim3(npq / 256), dim3(256), 0, stream,
                       xq, fc, fs, dflag_fc, NHQ, npq);
    hipLaunchKernelGGL(rope_kernel, dim3(npk / 256), dim3(256), 0, stream,
                       xk, fc, fs, dflag_fc, NKV_H, npk);

    hipLaunchKernelGGL(transpose_v_kernel, dim3(S_LEN / 32, HD_DIM / 32, BATCH * NKV_H),
                       dim3(256), 0, stream, xv, vt);

    hipLaunchKernelGGL(attn_mfma_kernel, dim3(BATCH * NHQ * (S_LEN / 64)), dim3(256), 0, stream,
                       xq, xk, vt, mnorm, att);

    // Final GEMM: A = att (bf16), B = wo (sniffed), C = d_out (f32).
    hipLaunchKernelGGL((gemm_bt_mfma<false>), dim3(M / 128, DMODEL / 128), dim3(256), 0, stream,
                       att, wo, d_out, M, DMODEL, DMODEL, dflag_x, 1, 2);
}

// Round 7
// 529.801 us; speedup vs baseline: 6.6256x; 1.6030x over previous
//
#include <hip/hip_runtime.h>
#include <hip/hip_bf16.h>
#include <cstdint>
#include <cstddef>

#define S_LEN   2048
#define NHQ     16
#define NKV_H   8
#define HD_DIM  128
#define DMODEL  2048
#define BATCH   2
#define KVD     (NKV_H * HD_DIM)   // 1024

typedef float f32x4  __attribute__((ext_vector_type(4)));
typedef __bf16 bf16x8 __attribute__((ext_vector_type(8)));

// ---------------------------------------------------------------------------
// async 16B global -> LDS (lane's 16B lands at ldsbase + lane*16)
// ---------------------------------------------------------------------------
__device__ __forceinline__ void gload_lds16(const __bf16* g, __bf16* l) {
    __builtin_amdgcn_global_load_lds(
        (const __attribute__((address_space(1))) void*)g,
        (__attribute__((address_space(3))) void*)l, 16, 0, 0);
}

// ---------------------------------------------------------------------------
// Dtype sniff for x: bf16 (flag=1) or f32 (flag=0)? Reads first 1024 dwords.
// ---------------------------------------------------------------------------
__global__ void sniff_x_kernel(const unsigned* __restrict__ x,
                               int* __restrict__ flag) {
    __shared__ int cnt;
    if (threadIdx.x == 0) cnt = 0;
    __syncthreads();
    int c = 0;
    for (int j = threadIdx.x; j < 1024; j += 256) {
        unsigned hw = x[j] & 0xFFFFu;
        unsigned e  = (hw >> 7) & 0xFF;
        if (hw == 0u || (e >= 118 && e <= 132)) c++;
    }
    atomicAdd(&cnt, c);
    __syncthreads();
    if (threadIdx.x == 0) *flag = (cnt > 512) ? 1 : 0;
}

__global__ void sniff_fc_kernel(const unsigned* __restrict__ fc,
                                int* __restrict__ flag) {
    if (threadIdx.x == 0) *flag = (fc[0] == 0x3F803F80u) ? 1 : 0;
}

// ---------------------------------------------------------------------------
// Mask normalization with layout sniffing (u8 / i32 / f32 / bf16).
// ---------------------------------------------------------------------------
__global__ void mask_norm_kernel(const unsigned char* __restrict__ mraw,
                                 unsigned char* __restrict__ mout, int n) {
    __shared__ int f_bf16, f_f32, f_u8;
    if (threadIdx.x == 0) { f_bf16 = 0; f_f32 = 0; f_u8 = 0; }
    __syncthreads();
    const unsigned* dw = (const unsigned*)mraw;
    int ndw = n / 4;
    for (int j = threadIdx.x; j < ndw; j += blockDim.x) {
        unsigned v = dw[j];
        if (v == 0x00003F80u || v == 0x3F803F80u) f_bf16 = 1;
        else if (v == 0x3F800000u) f_f32 = 1;
        else if (v & 0xFFFFFFFEu) f_u8 = 1;
    }
    __syncthreads();
    int layout;              // 0=u8 1=i32 2=f32 3=bf16
    if (f_bf16) layout = 3;
    else if (f_f32) layout = 2;
    else if (f_u8) layout = 0;
    else layout = 1;
    for (int i = threadIdx.x; i < n; i += blockDim.x) {
        unsigned v;
        if (layout == 0)      v = mraw[i];
        else if (layout == 3) v = ((const unsigned short*)mraw)[i];
        else                  v = ((const unsigned*)mraw)[i];
        mout[i] = v ? 1u : 0u;
    }
}

// ---------------------------------------------------------------------------
// Bulk convert to bf16 (or copy if already bf16). 8 elems/thread.
// ---------------------------------------------------------------------------
__global__ __launch_bounds__(256)
void conv_bf16_kernel(const void* __restrict__ src, __bf16* __restrict__ dst,
                      int n8, const int* __restrict__ dflag) {
    int i = blockIdx.x * blockDim.x + threadIdx.x;
    if (i >= n8) return;
    size_t off = (size_t)i * 8;
    if (*dflag) {
        *reinterpret_cast<uint4*>(dst + off) =
            *reinterpret_cast<const uint4*>((const __bf16*)src + off);
    } else {
        const float* f = (const float*)src + off;
        float4 a = *reinterpret_cast<const float4*>(f);
        float4 b = *reinterpret_cast<const float4*>(f + 4);
        bf16x8 v;
        v[0] = (__bf16)a.x; v[1] = (__bf16)a.y; v[2] = (__bf16)a.z; v[3] = (__bf16)a.w;
        v[4] = (__bf16)b.x; v[5] = (__bf16)b.y; v[6] = (__bf16)b.z; v[7] = (__bf16)b.w;
        *reinterpret_cast<bf16x8*>(dst + off) = v;
    }
}

// ---------------------------------------------------------------------------
// m97-style MFMA GEMM: C[M,N] = A[M,K] @ Bw[N,K]^T, bf16 inputs, fp32 acc.
// 128x128 tile, BK=64, global_load_lds width=16 into UNPADDED LDS with
// XOR granule swizzle: LDS[r][g] holds global granule g ^ (r&7) (granule =
// 16B = 8 halves). MFMA b128 reads then hit 8 distinct 4-bank groups
// (2-way alias only = free), staging is wave-uniform-base compliant.
//   A/B frag: elem j of lane -> [m|n = lane&15][k = (lane>>4)*8 + j]
//   C/D:      lane reg r     -> [row = (lane>>4)*4 + r][col = lane&15]
// ---------------------------------------------------------------------------
template <bool OUT_BF16>
__global__ __launch_bounds__(256)
void gemm_bt_async(const __bf16* __restrict__ A, const __bf16* __restrict__ Bw,
                   void* __restrict__ Cv, int M, int N, int K) {
    __shared__ __align__(16) __bf16 As[128 * 64];
    __shared__ __align__(16) __bf16 Bs[128 * 64];

    const int t    = threadIdx.x;
    const int w    = t >> 6;
    const int lane = t & 63;
    const int quad = lane >> 4;
    const int l16  = lane & 15;
    const int wm   = (w >> 1) * 64;
    const int wn   = (w & 1) * 64;
    const int m0   = blockIdx.x * 128;
    const int n0   = blockIdx.y * 128;
    const int rl   = lane >> 3;   // row within 8-row staging chunk
    const int gl   = lane & 7;    // LDS granule slot
    const int swA  = (quad) ;     // unused placeholder to keep regs tight

    f32x4 acc[4][4];
#pragma unroll
    for (int i = 0; i < 4; ++i)
#pragma unroll
        for (int j = 0; j < 4; ++j) acc[i][j] = (f32x4){0.f, 0.f, 0.f, 0.f};

    for (int k0 = 0; k0 < K; k0 += 64) {
        __syncthreads();   // previous iteration's LDS reads complete
        // wave w stages rows w*32 .. w*32+31 of both tiles (4 chunks x 8 rows)
#pragma unroll
        for (int p = 0; p < 4; ++p) {
            const int rowb = w * 32 + p * 8;
            const int r    = rowb + rl;
            const int gA   = gl ^ rl;     // global granule to fetch (r&7 == rl)
            gload_lds16(A  + (size_t)(m0 + r) * K + k0 + gA * 8, &As[rowb * 64]);
            gload_lds16(Bw + (size_t)(n0 + r) * K + k0 + gA * 8, &Bs[rowb * 64]);
        }
        __syncthreads();   // drains vmcnt before use
#pragma unroll
        for (int ks = 0; ks < 2; ++ks) {
            const int G = ks * 4 + quad;          // logical granule (k-slab)
            const int gsw = (G ^ (l16 & 7)) * 8;  // swizzled halves offset
            bf16x8 af[4], bf[4];
#pragma unroll
            for (int i = 0; i < 4; ++i)
                af[i] = *reinterpret_cast<const bf16x8*>(
                    &As[(wm + i * 16 + l16) * 64 + gsw]);
#pragma unroll
            for (int j = 0; j < 4; ++j)
                bf[j] = *reinterpret_cast<const bf16x8*>(
                    &Bs[(wn + j * 16 + l16) * 64 + gsw]);
#pragma unroll
            for (int i = 0; i < 4; ++i)
#pragma unroll
                for (int j = 0; j < 4; ++j)
                    acc[i][j] = __builtin_amdgcn_mfma_f32_16x16x32_bf16(
                        af[i], bf[j], acc[i][j], 0, 0, 0);
        }
    }
    (void)swA;
#pragma unroll
    for (int i = 0; i < 4; ++i)
#pragma unroll
        for (int r = 0; r < 4; ++r) {
            size_t m = (size_t)(m0 + wm + i * 16 + quad * 4 + r);
#pragma unroll
            for (int j = 0; j < 4; ++j) {
                int n = n0 + wn + j * 16 + l16;
                if constexpr (OUT_BF16)
                    ((__hip_bfloat16*)Cv)[m * N + n] = __float2bfloat16(acc[i][j][r]);
                else
                    ((float*)Cv)[m * N + n] = acc[i][j][r];
            }
        }
}

// ---------------------------------------------------------------------------
// RoPE in-place on bf16 [B*S, nheads*128]; pair i rotates (2i, 2i+1).
// ---------------------------------------------------------------------------
__global__ void rope_kernel(__hip_bfloat16* __restrict__ xqk,
                            const void* __restrict__ cosv,
                            const void* __restrict__ sinv,
                            const int* __restrict__ dflag_fc,
                            int nheads, int npairs) {
    int idx = blockIdx.x * blockDim.x + threadIdx.x;
    if (idx >= npairs) return;
    int i  = idx & 63;
    int h  = (idx >> 6) % nheads;
    int bs = idx / (64 * nheads);
    int s  = bs & (S_LEN - 1);
    float c, sn;
    if (*dflag_fc) {
        c  = __bfloat162float(((const __hip_bfloat16*)cosv)[s * 64 + i]);
        sn = __bfloat162float(((const __hip_bfloat16*)sinv)[s * 64 + i]);
    } else {
        c  = ((const float*)cosv)[s * 64 + i];
        sn = ((const float*)sinv)[s * 64 + i];
    }
    unsigned* p = (unsigned*)(xqk + (size_t)bs * (nheads * HD_DIM) + h * HD_DIM) + i;
    unsigned u = *p;
    float xr = __uint_as_float(u << 16);
    float xi = __uint_as_float(u & 0xFFFF0000u);
    float o0 = xr * c - xi * sn;
    float o1 = xr * sn + xi * c;
    union { __hip_bfloat16 h2[2]; unsigned u32; } out;
    out.h2[0] = __float2bfloat16(o0);
    out.h2[1] = __float2bfloat16(o1);
    *p = out.u32;
}

// ---------------------------------------------------------------------------
// V transpose: xv [B*S][KVD] -> vt [(b*NKV+kv)*128 + d][S]. 32x32 LDS tiles.
// ---------------------------------------------------------------------------
__global__ __launch_bounds__(256)
void transpose_v_kernel(const __hip_bfloat16* __restrict__ xv,
                        __hip_bfloat16* __restrict__ vt) {
    __shared__ unsigned short T[32][36];
    const int t  = threadIdx.x;
    const int s0 = blockIdx.x * 32;
    const int d0 = blockIdx.y * 32;
    const int z  = blockIdx.z;           // b*NKV + kv
    const int b  = z >> 3;
    const int kv = z & 7;
    {
        int sr = t >> 3, dc = (t & 7) * 4;
        const unsigned short* p = (const unsigned short*)xv
            + (size_t)(b * S_LEN + s0 + sr) * KVD + kv * 128 + d0 + dc;
        uint2 v = *reinterpret_cast<const uint2*>(p);
        T[sr][dc + 0] = (unsigned short)(v.x & 0xFFFFu);
        T[sr][dc + 1] = (unsigned short)(v.x >> 16);
        T[sr][dc + 2] = (unsigned short)(v.y & 0xFFFFu);
        T[sr][dc + 3] = (unsigned short)(v.y >> 16);
    }
    __syncthreads();
    {
        int dr = t >> 3, sc = (t & 7) * 4;
        unsigned w0 = (unsigned)T[sc + 0][dr] | ((unsigned)T[sc + 1][dr] << 16);
        unsigned w1 = (unsigned)T[sc + 2][dr] | ((unsigned)T[sc + 3][dr] << 16);
        unsigned short* q = (unsigned short*)vt
            + ((size_t)z * 128 + d0 + dr) * S_LEN + s0 + sc;
        uint2 v; v.x = w0; v.y = w1;
        *reinterpret_cast<uint2*>(q) = v;
    }
}

// ---------------------------------------------------------------------------
// MFMA flash attention (round-5/6 proven, unchanged).
// ---------------------------------------------------------------------------
__global__ __launch_bounds__(256)
void attn_mfma_kernel(const __hip_bfloat16* xq,
                      const __hip_bfloat16* __restrict__ xk,
                      const __hip_bfloat16* __restrict__ vt_g,
                      const unsigned char* __restrict__ msk,
                      __hip_bfloat16* att) {
    __shared__ __bf16 Qs[64][136];
    __shared__ __bf16 Ks[64][136];
    __shared__ __bf16 Vt[128][72];
    __shared__ __bf16 Ps[4][16][72];

    const int t    = threadIdx.x;
    const int w    = t >> 6;
    const int lane = t & 63;
    const int quad = lane >> 4;
    const int l16  = lane & 15;

    const int bid = blockIdx.x;
    const int qt  = bid & 31;
    const int h   = (bid >> 5) & (NHQ - 1);
    const int b   = bid >> 9;
    const int kvh = h >> 1;
    const int q0  = qt * 64;

#pragma unroll
    for (int i = 0; i < 4; ++i) {
        int p = t + i * 256;
        int r = p >> 4, c = p & 15;
        *reinterpret_cast<uint4*>(&Qs[r][c * 8]) =
            *reinterpret_cast<const uint4*>((const unsigned short*)xq
                + (size_t)(b * S_LEN + q0 + r) * DMODEL + h * 128 + c * 8);
    }

    float m_r[4], l_r[4];
    f32x4 o[8];
#pragma unroll
    for (int r = 0; r < 4; ++r) { m_r[r] = -INFINITY; l_r[r] = 0.f; }
#pragma unroll
    for (int d0 = 0; d0 < 8; ++d0) o[d0] = (f32x4){0.f, 0.f, 0.f, 0.f};

    const float scale = 0.08838834764831845f;  // 1/sqrt(128)

    for (int k0 = 0; k0 < S_LEN; k0 += 64) {
        __syncthreads();
#pragma unroll
        for (int i = 0; i < 4; ++i) {
            int p = t + i * 256;
            int r = p >> 4, c = p & 15;
            *reinterpret_cast<uint4*>(&Ks[r][c * 8]) =
                *reinterpret_cast<const uint4*>((const unsigned short*)xk
                    + (size_t)(b * S_LEN + k0 + r) * KVD + kvh * 128 + c * 8);
        }
#pragma unroll
        for (int i = 0; i < 4; ++i) {
            int p = t + i * 256;
            int d = p >> 3, c = p & 7;
            *reinterpret_cast<uint4*>(&Vt[d][c * 8]) =
                *reinterpret_cast<const uint4*>((const unsigned short*)vt_g
                    + ((size_t)(b * NKV_H + kvh) * 128 + d) * S_LEN + k0 + c * 8);
        }
        int mk[4];
#pragma unroll
        for (int n0 = 0; n0 < 4; ++n0)
            mk[n0] = msk[b * S_LEN + k0 + n0 * 16 + l16];
        __syncthreads();

        f32x4 sc4[4];
#pragma unroll
        for (int n0 = 0; n0 < 4; ++n0) sc4[n0] = (f32x4){0.f, 0.f, 0.f, 0.f};
#pragma unroll
        for (int ks = 0; ks < 4; ++ks) {
            int khd = ks * 32 + quad * 8;
            bf16x8 af = *reinterpret_cast<const bf16x8*>(&Qs[w * 16 + l16][khd]);
#pragma unroll
            for (int n0 = 0; n0 < 4; ++n0) {
                bf16x8 bf = *reinterpret_cast<const bf16x8*>(&Ks[n0 * 16 + l16][khd]);
                sc4[n0] = __builtin_amdgcn_mfma_f32_16x16x32_bf16(af, bf, sc4[n0], 0, 0, 0);
            }
        }

#pragma unroll
        for (int n0 = 0; n0 < 4; ++n0)
#pragma unroll
            for (int r = 0; r < 4; ++r) {
                float v = sc4[n0][r] * scale;
                sc4[n0][r] = mk[n0] ? -INFINITY : v;
            }
        float alpha[4];
#pragma unroll
        for (int r = 0; r < 4; ++r) {
            float rmax = fmaxf(fmaxf(sc4[0][r], sc4[1][r]), fmaxf(sc4[2][r], sc4[3][r]));
#pragma unroll
            for (int m = 1; m < 16; m <<= 1)
                rmax = fmaxf(rmax, __shfl_xor(rmax, m, 64));
            float mn = fmaxf(m_r[r], rmax);
            alpha[r] = __expf(m_r[r] - mn);
            m_r[r] = mn;
            float rs = 0.f;
#pragma unroll
            for (int n0 = 0; n0 < 4; ++n0) {
                float p = __expf(sc4[n0][r] - mn);
                sc4[n0][r] = p;
                rs += p;
            }
#pragma unroll
            for (int m = 1; m < 16; m <<= 1)
                rs += __shfl_xor(rs, m, 64);
            l_r[r] = l_r[r] * alpha[r] + rs;
        }
#pragma unroll
        for (int d0 = 0; d0 < 8; ++d0)
#pragma unroll
            for (int r = 0; r < 4; ++r) o[d0][r] *= alpha[r];

#pragma unroll
        for (int n0 = 0; n0 < 4; ++n0)
#pragma unroll
            for (int r = 0; r < 4; ++r)
                Ps[w][quad * 4 + r][n0 * 16 + l16] = (__bf16)sc4[n0][r];

#pragma unroll
        for (int kk = 0; kk < 64; kk += 32) {
            bf16x8 af = *reinterpret_cast<const bf16x8*>(&Ps[w][l16][kk + quad * 8]);
#pragma unroll
            for (int d0 = 0; d0 < 8; ++d0) {
                bf16x8 bf = *reinterpret_cast<const bf16x8*>(&Vt[d0 * 16 + l16][kk + quad * 8]);
                o[d0] = __builtin_amdgcn_mfma_f32_16x16x32_bf16(af, bf, o[d0], 0, 0, 0);
            }
        }
    }

    float inv[4];
#pragma unroll
    for (int r = 0; r < 4; ++r) inv[r] = 1.f / l_r[r];
#pragma unroll
    for (int d0 = 0; d0 < 8; ++d0)
#pragma unroll
        for (int r = 0; r < 4; ++r) {
            size_t row = (size_t)(b * S_LEN + q0 + w * 16 + quad * 4 + r);
            att[row * DMODEL + h * 128 + d0 * 16 + l16] =
                __float2bfloat16(o[d0][r] * inv[r]);
        }
}

// ---------------------------------------------------------------------------
extern "C" void kernel_launch(void* const* d_in, const int* in_sizes, int n_in,
                              void* d_out, int out_size, void* d_ws, size_t ws_size,
                              hipStream_t stream) {
    const void* x  = d_in[0];
    const void* wq = d_in[1];
    const void* wk = d_in[2];
    const void* wv = d_in[3];
    const void* wo = d_in[4];
    const void* fc = d_in[5];
    const void* fs = d_in[6];
    const unsigned char* mraw = (const unsigned char*)d_in[7];

    const int M = BATCH * S_LEN;                                 // 4096
    // ws (proven 32 MB + 8 KB): control, xq(16M, att aliases), xk(8M), xv(8M).
    char* wsb = (char*)d_ws;
    int* dflag_x  = (int*)wsb;
    int* dflag_fc = (int*)(wsb + 64);
    unsigned char* mnorm = (unsigned char*)(wsb + 128);
    __hip_bfloat16* xq = (__hip_bfloat16*)(wsb + 8192);
    __hip_bfloat16* xk = xq + (size_t)M * DMODEL;
    __hip_bfloat16* xv = xk + (size_t)M * KVD;
    __hip_bfloat16* att = xq;                       // alias (safe, see attn)
    __hip_bfloat16* wob = xk;                       // reuses xk after attn (8 MB)

    // d_out (32 MB f32) as staging scratch before its final write:
    //   xb@0 (16M), wqb@16M (8M), wkb@24M (4M), wvb@28M (4M);
    //   vt@0 (8M) after QKV GEMMs (xb dead).
    char* dob = (char*)d_out;
    __bf16* xb  = (__bf16*)dob;
    __bf16* wqb = (__bf16*)(dob + (16u << 20));
    __bf16* wkb = (__bf16*)(dob + (24u << 20));
    __bf16* wvb = (__bf16*)(dob + (28u << 20));
    __hip_bfloat16* vt = (__hip_bfloat16*)d_out;

    hipLaunchKernelGGL(sniff_x_kernel, dim3(1), dim3(256), 0, stream,
                       (const unsigned*)x, dflag_x);
    hipLaunchKernelGGL(sniff_fc_kernel, dim3(1), dim3(64), 0, stream,
                       (const unsigned*)fc, dflag_fc);
    hipLaunchKernelGGL(mask_norm_kernel, dim3(1), dim3(256), 0, stream,
                       mraw, mnorm, BATCH * S_LEN);

    // converts (to d_out scratch)
    hipLaunchKernelGGL(conv_bf16_kernel, dim3((M * DMODEL / 8) / 256), dim3(256), 0, stream,
                       x, xb, M * DMODEL / 8, dflag_x);
    hipLaunchKernelGGL(conv_bf16_kernel, dim3((DMODEL * DMODEL / 8) / 256), dim3(256), 0, stream,
                       wq, wqb, DMODEL * DMODEL / 8, dflag_x);
    hipLaunchKernelGGL(conv_bf16_kernel, dim3((KVD * DMODEL / 8) / 256), dim3(256), 0, stream,
                       wk, wkb, KVD * DMODEL / 8, dflag_x);
    hipLaunchKernelGGL(conv_bf16_kernel, dim3((KVD * DMODEL / 8) / 256), dim3(256), 0, stream,
                       wv, wvb, KVD * DMODEL / 8, dflag_x);

    hipLaunchKernelGGL((gemm_bt_async<true>), dim3(M / 128, DMODEL / 128), dim3(256), 0, stream,
                       xb, wqb, (void*)xq, M, DMODEL, DMODEL);
    hipLaunchKernelGGL((gemm_bt_async<true>), dim3(M / 128, KVD / 128), dim3(256), 0, stream,
                       xb, wkb, (void*)xk, M, KVD, DMODEL);
    hipLaunchKernelGGL((gemm_bt_async<true>), dim3(M / 128, KVD / 128), dim3(256), 0, stream,
                       xb, wvb, (void*)xv, M, KVD, DMODEL);

    int npq = M * NHQ * (HD_DIM / 2);
    int npk = M * NKV_H * (HD_DIM / 2);
    hipLaunchKernelGGL(rope_kernel, dim3(npq / 256), dim3(256), 0, stream,
                       xq, fc, fs, dflag_fc, NHQ, npq);
    hipLaunchKernelGGL(rope_kernel, dim3(npk / 256), dim3(256), 0, stream,
                       xk, fc, fs, dflag_fc, NKV_H, npk);

    hipLaunchKernelGGL(transpose_v_kernel, dim3(S_LEN / 32, HD_DIM / 32, BATCH * NKV_H),
                       dim3(256), 0, stream, xv, vt);

    hipLaunchKernelGGL(attn_mfma_kernel, dim3(BATCH * NHQ * (S_LEN / 64)), dim3(256), 0, stream,
                       xq, xk, vt, mnorm, att);

    // wo -> bf16 into the dead xk region, then final GEMM writes d_out (f32).
    hipLaunchKernelGGL(conv_bf16_kernel, dim3((DMODEL * DMODEL / 8) / 256), dim3(256), 0, stream,
                       wo, (__bf16*)wob, DMODEL * DMODEL / 8, dflag_x);
    hipLaunchKernelGGL((gemm_bt_async<false>), dim3(M / 128, DMODEL / 128), dim3(256), 0, stream,
                       (const __bf16*)att, (const __bf16*)wob, d_out, M, DMODEL, DMODEL);
}

// Round 8
// 521.243 us; speedup vs baseline: 6.7344x; 1.0164x over previous
//
#include <hip/hip_runtime.h>
#include <hip/hip_bf16.h>
#include <cstdint>
#include <cstddef>

#define S_LEN   2048
#define NHQ     16
#define NKV_H   8
#define HD_DIM  128
#define DMODEL  2048
#define BATCH   2
#define KVD     (NKV_H * HD_DIM)   // 1024

typedef float f32x4  __attribute__((ext_vector_type(4)));
typedef __bf16 bf16x8 __attribute__((ext_vector_type(8)));

// ---------------------------------------------------------------------------
// async 16B global -> LDS (lane's 16B lands at ldsbase + lane*16)
// ---------------------------------------------------------------------------
__device__ __forceinline__ void gload_lds16(const __bf16* g, __bf16* l) {
    __builtin_amdgcn_global_load_lds(
        (const __attribute__((address_space(1))) void*)g,
        (__attribute__((address_space(3))) void*)l, 16, 0, 0);
}

// ---------------------------------------------------------------------------
// Dtype sniff for x: bf16 (flag=1) or f32 (flag=0)? Reads first 1024 dwords.
// ---------------------------------------------------------------------------
__global__ void sniff_x_kernel(const unsigned* __restrict__ x,
                               int* __restrict__ flag) {
    __shared__ int cnt;
    if (threadIdx.x == 0) cnt = 0;
    __syncthreads();
    int c = 0;
    for (int j = threadIdx.x; j < 1024; j += 256) {
        unsigned hw = x[j] & 0xFFFFu;
        unsigned e  = (hw >> 7) & 0xFF;
        if (hw == 0u || (e >= 118 && e <= 132)) c++;
    }
    atomicAdd(&cnt, c);
    __syncthreads();
    if (threadIdx.x == 0) *flag = (cnt > 512) ? 1 : 0;
}

__global__ void sniff_fc_kernel(const unsigned* __restrict__ fc,
                                int* __restrict__ flag) {
    if (threadIdx.x == 0) *flag = (fc[0] == 0x3F803F80u) ? 1 : 0;
}

// ---------------------------------------------------------------------------
// Mask normalization with layout sniffing (u8 / i32 / f32 / bf16).
// ---------------------------------------------------------------------------
__global__ void mask_norm_kernel(const unsigned char* __restrict__ mraw,
                                 unsigned char* __restrict__ mout, int n) {
    __shared__ int f_bf16, f_f32, f_u8;
    if (threadIdx.x == 0) { f_bf16 = 0; f_f32 = 0; f_u8 = 0; }
    __syncthreads();
    const unsigned* dw = (const unsigned*)mraw;
    int ndw = n / 4;
    for (int j = threadIdx.x; j < ndw; j += blockDim.x) {
        unsigned v = dw[j];
        if (v == 0x00003F80u || v == 0x3F803F80u) f_bf16 = 1;
        else if (v == 0x3F800000u) f_f32 = 1;
        else if (v & 0xFFFFFFFEu) f_u8 = 1;
    }
    __syncthreads();
    int layout;              // 0=u8 1=i32 2=f32 3=bf16
    if (f_bf16) layout = 3;
    else if (f_f32) layout = 2;
    else if (f_u8) layout = 0;
    else layout = 1;
    for (int i = threadIdx.x; i < n; i += blockDim.x) {
        unsigned v;
        if (layout == 0)      v = mraw[i];
        else if (layout == 3) v = ((const unsigned short*)mraw)[i];
        else                  v = ((const unsigned*)mraw)[i];
        mout[i] = v ? 1u : 0u;
    }
}

// ---------------------------------------------------------------------------
// Bulk convert to bf16 (or copy if already bf16). 8 elems/thread.
// ---------------------------------------------------------------------------
__global__ __launch_bounds__(256)
void conv_bf16_kernel(const void* __restrict__ src, __bf16* __restrict__ dst,
                      int n8, const int* __restrict__ dflag) {
    int i = blockIdx.x * blockDim.x + threadIdx.x;
    if (i >= n8) return;
    size_t off = (size_t)i * 8;
    if (*dflag) {
        *reinterpret_cast<uint4*>(dst + off) =
            *reinterpret_cast<const uint4*>((const __bf16*)src + off);
    } else {
        const float* f = (const float*)src + off;
        float4 a = *reinterpret_cast<const float4*>(f);
        float4 b = *reinterpret_cast<const float4*>(f + 4);
        bf16x8 v;
        v[0] = (__bf16)a.x; v[1] = (__bf16)a.y; v[2] = (__bf16)a.z; v[3] = (__bf16)a.w;
        v[4] = (__bf16)b.x; v[5] = (__bf16)b.y; v[6] = (__bf16)b.z; v[7] = (__bf16)b.w;
        *reinterpret_cast<bf16x8*>(dst + off) = v;
    }
}

// ---------------------------------------------------------------------------
// m97-style MFMA GEMM (round-7 proven): C = A @ Bw^T, bf16 in, fp32 acc.
// ---------------------------------------------------------------------------
template <bool OUT_BF16>
__global__ __launch_bounds__(256)
void gemm_bt_async(const __bf16* __restrict__ A, const __bf16* __restrict__ Bw,
                   void* __restrict__ Cv, int M, int N, int K) {
    __shared__ __align__(16) __bf16 As[128 * 64];
    __shared__ __align__(16) __bf16 Bs[128 * 64];

    const int t    = threadIdx.x;
    const int w    = t >> 6;
    const int lane = t & 63;
    const int quad = lane >> 4;
    const int l16  = lane & 15;
    const int wm   = (w >> 1) * 64;
    const int wn   = (w & 1) * 64;
    const int m0   = blockIdx.x * 128;
    const int n0   = blockIdx.y * 128;
    const int rl   = lane >> 3;
    const int gl   = lane & 7;

    f32x4 acc[4][4];
#pragma unroll
    for (int i = 0; i < 4; ++i)
#pragma unroll
        for (int j = 0; j < 4; ++j) acc[i][j] = (f32x4){0.f, 0.f, 0.f, 0.f};

    for (int k0 = 0; k0 < K; k0 += 64) {
        __syncthreads();
#pragma unroll
        for (int p = 0; p < 4; ++p) {
            const int rowb = w * 32 + p * 8;
            const int r    = rowb + rl;
            const int gA   = gl ^ rl;
            gload_lds16(A  + (size_t)(m0 + r) * K + k0 + gA * 8, &As[rowb * 64]);
            gload_lds16(Bw + (size_t)(n0 + r) * K + k0 + gA * 8, &Bs[rowb * 64]);
        }
        __syncthreads();
#pragma unroll
        for (int ks = 0; ks < 2; ++ks) {
            const int G = ks * 4 + quad;
            const int gsw = (G ^ (l16 & 7)) * 8;
            bf16x8 af[4], bf[4];
#pragma unroll
            for (int i = 0; i < 4; ++i)
                af[i] = *reinterpret_cast<const bf16x8*>(
                    &As[(wm + i * 16 + l16) * 64 + gsw]);
#pragma unroll
            for (int j = 0; j < 4; ++j)
                bf[j] = *reinterpret_cast<const bf16x8*>(
                    &Bs[(wn + j * 16 + l16) * 64 + gsw]);
#pragma unroll
            for (int i = 0; i < 4; ++i)
#pragma unroll
                for (int j = 0; j < 4; ++j)
                    acc[i][j] = __builtin_amdgcn_mfma_f32_16x16x32_bf16(
                        af[i], bf[j], acc[i][j], 0, 0, 0);
        }
    }
#pragma unroll
    for (int i = 0; i < 4; ++i)
#pragma unroll
        for (int r = 0; r < 4; ++r) {
            size_t m = (size_t)(m0 + wm + i * 16 + quad * 4 + r);
#pragma unroll
            for (int j = 0; j < 4; ++j) {
                int n = n0 + wn + j * 16 + l16;
                if constexpr (OUT_BF16)
                    ((__hip_bfloat16*)Cv)[m * N + n] = __float2bfloat16(acc[i][j][r]);
                else
                    ((float*)Cv)[m * N + n] = acc[i][j][r];
            }
        }
}

// ---------------------------------------------------------------------------
// RoPE in-place on bf16 [B*S, nheads*128]; pair i rotates (2i, 2i+1).
// ---------------------------------------------------------------------------
__global__ void rope_kernel(__hip_bfloat16* __restrict__ xqk,
                            const void* __restrict__ cosv,
                            const void* __restrict__ sinv,
                            const int* __restrict__ dflag_fc,
                            int nheads, int npairs) {
    int idx = blockIdx.x * blockDim.x + threadIdx.x;
    if (idx >= npairs) return;
    int i  = idx & 63;
    int h  = (idx >> 6) % nheads;
    int bs = idx / (64 * nheads);
    int s  = bs & (S_LEN - 1);
    float c, sn;
    if (*dflag_fc) {
        c  = __bfloat162float(((const __hip_bfloat16*)cosv)[s * 64 + i]);
        sn = __bfloat162float(((const __hip_bfloat16*)sinv)[s * 64 + i]);
    } else {
        c  = ((const float*)cosv)[s * 64 + i];
        sn = ((const float*)sinv)[s * 64 + i];
    }
    unsigned* p = (unsigned*)(xqk + (size_t)bs * (nheads * HD_DIM) + h * HD_DIM) + i;
    unsigned u = *p;
    float xr = __uint_as_float(u << 16);
    float xi = __uint_as_float(u & 0xFFFF0000u);
    float o0 = xr * c - xi * sn;
    float o1 = xr * sn + xi * c;
    union { __hip_bfloat16 h2[2]; unsigned u32; } out;
    out.h2[0] = __float2bfloat16(o0);
    out.h2[1] = __float2bfloat16(o1);
    *p = out.u32;
}

// ---------------------------------------------------------------------------
// V transpose: xv [B*S][KVD] -> vt [(b*NKV+kv)*128 + d][S]. 32x32 LDS tiles.
// ---------------------------------------------------------------------------
__global__ __launch_bounds__(256)
void transpose_v_kernel(const __hip_bfloat16* __restrict__ xv,
                        __hip_bfloat16* __restrict__ vt) {
    __shared__ unsigned short T[32][36];
    const int t  = threadIdx.x;
    const int s0 = blockIdx.x * 32;
    const int d0 = blockIdx.y * 32;
    const int z  = blockIdx.z;           // b*NKV + kv
    const int b  = z >> 3;
    const int kv = z & 7;
    {
        int sr = t >> 3, dc = (t & 7) * 4;
        const unsigned short* p = (const unsigned short*)xv
            + (size_t)(b * S_LEN + s0 + sr) * KVD + kv * 128 + d0 + dc;
        uint2 v = *reinterpret_cast<const uint2*>(p);
        T[sr][dc + 0] = (unsigned short)(v.x & 0xFFFFu);
        T[sr][dc + 1] = (unsigned short)(v.x >> 16);
        T[sr][dc + 2] = (unsigned short)(v.y & 0xFFFFu);
        T[sr][dc + 3] = (unsigned short)(v.y >> 16);
    }
    __syncthreads();
    {
        int dr = t >> 3, sc = (t & 7) * 4;
        unsigned w0 = (unsigned)T[sc + 0][dr] | ((unsigned)T[sc + 1][dr] << 16);
        unsigned w1 = (unsigned)T[sc + 2][dr] | ((unsigned)T[sc + 3][dr] << 16);
        unsigned short* q = (unsigned short*)vt
            + ((size_t)z * 128 + d0 + dr) * S_LEN + s0 + sc;
        uint2 v; v.x = w0; v.y = w1;
        *reinterpret_cast<uint2*>(q) = v;
    }
}

// ---------------------------------------------------------------------------
// MFMA flash attention v2: Q in registers, XOR-swizzled unpadded LDS
// (40960 B exactly -> 4 blocks/CU), global_load_lds staging, exp2 softmax.
// Layout rule: LDS row r slot s (16B granules) holds global granule s^(r&7);
// MFMA b128 read of logical granule G uses slot G^(r&7) -> bank-uniform.
// att aliases xq (block reads its own Q region into regs before any write).
// ---------------------------------------------------------------------------
__global__ __launch_bounds__(256)
void attn_mfma2_kernel(const __hip_bfloat16* xq,
                       const __hip_bfloat16* __restrict__ xk,
                       const __hip_bfloat16* __restrict__ vt_g,
                       const unsigned char* __restrict__ msk,
                       __hip_bfloat16* att) {
    __shared__ __align__(16) __bf16 Ks[64 * 128];   // 16384 B, 16 granules/row
    __shared__ __align__(16) __bf16 Vt[128 * 64];   // 16384 B, 8 granules/row
    __shared__ __align__(16) __bf16 Ps[4][16][64];  //  8192 B, 8 granules/row

    const int t    = threadIdx.x;
    const int w    = t >> 6;
    const int lane = t & 63;
    const int quad = lane >> 4;
    const int l16  = lane & 15;

    const int bid = blockIdx.x;
    const int qt  = bid & 31;
    const int h   = (bid >> 5) & (NHQ - 1);
    const int b   = bid >> 9;
    const int kvh = h >> 1;
    const int q0  = qt * 64;

    // ---- Q fragments in registers: wave w owns q rows w*16..w*16+15 ----
    bf16x8 qf[4];
    {
        const __bf16* qrow = (const __bf16*)xq
            + (size_t)(b * S_LEN + q0 + w * 16 + l16) * DMODEL + h * 128 + quad * 8;
#pragma unroll
        for (int ks = 0; ks < 4; ++ks)
            qf[ks] = *reinterpret_cast<const bf16x8*>(qrow + ks * 32);
    }

    float m_r[4], l_r[4];
    f32x4 o[8];
#pragma unroll
    for (int r = 0; r < 4; ++r) { m_r[r] = -INFINITY; l_r[r] = 0.f; }
#pragma unroll
    for (int d0 = 0; d0 < 8; ++d0) o[d0] = (f32x4){0.f, 0.f, 0.f, 0.f};

    // softmax in log2 domain: scale2 = (1/sqrt(128)) * log2(e)
    const float scale2 = 0.08838834764831845f * 1.4426950408889634f;

    const int krl = lane >> 4, kgl = lane & 15;   // K staging: 4 rows x 16 gran
    const int vrl = lane >> 3, vgl = lane & 7;    // Vt staging: 8 rows x 8 gran

    for (int k0 = 0; k0 < S_LEN; k0 += 64) {
        __syncthreads();   // previous tile's LDS reads complete
        // ---- stage K tile: wave w rows w*16..+15, 4 async wave-loads ----
#pragma unroll
        for (int p = 0; p < 4; ++p) {
            const int row  = w * 16 + p * 4 + krl;
            const int srcg = kgl ^ (row & 7);
            gload_lds16((const __bf16*)xk + (size_t)(b * S_LEN + k0 + row) * KVD
                            + kvh * 128 + srcg * 8,
                        &Ks[(w * 16 + p * 4) * 128]);
        }
        // ---- stage V^T tile: wave w rows w*32..+31, 4 async wave-loads ----
#pragma unroll
        for (int p = 0; p < 4; ++p) {
            const int row  = w * 32 + p * 8 + vrl;
            const int srcg = vgl ^ (row & 7);
            gload_lds16((const __bf16*)vt_g
                            + ((size_t)(b * NKV_H + kvh) * 128 + row) * S_LEN
                            + k0 + srcg * 8,
                        &Vt[(w * 32 + p * 8) * 64]);
        }
        int mk[4];
#pragma unroll
        for (int n0 = 0; n0 < 4; ++n0)
            mk[n0] = msk[b * S_LEN + k0 + n0 * 16 + l16];
        __syncthreads();   // drains vmcnt (global_load_lds) for all waves

        // ---- QK^T: 16 q-rows x 64 keys ----
        f32x4 sc4[4];
#pragma unroll
        for (int n0 = 0; n0 < 4; ++n0) sc4[n0] = (f32x4){0.f, 0.f, 0.f, 0.f};
#pragma unroll
        for (int ks = 0; ks < 4; ++ks) {
            const int G = ks * 4 + quad;
#pragma unroll
            for (int n0 = 0; n0 < 4; ++n0) {
                const int row  = n0 * 16 + l16;
                const int slot = G ^ (row & 7);
                bf16x8 bf = *reinterpret_cast<const bf16x8*>(&Ks[row * 128 + slot * 8]);
                sc4[n0] = __builtin_amdgcn_mfma_f32_16x16x32_bf16(qf[ks], bf, sc4[n0], 0, 0, 0);
            }
        }

        // ---- scale + mask + online softmax (log2 domain) ----
#pragma unroll
        for (int n0 = 0; n0 < 4; ++n0)
#pragma unroll
            for (int r = 0; r < 4; ++r) {
                float v = sc4[n0][r] * scale2;
                sc4[n0][r] = mk[n0] ? -INFINITY : v;
            }
        float alpha[4];
#pragma unroll
        for (int r = 0; r < 4; ++r) {
            float rmax = fmaxf(fmaxf(sc4[0][r], sc4[1][r]), fmaxf(sc4[2][r], sc4[3][r]));
#pragma unroll
            for (int m = 1; m < 16; m <<= 1)
                rmax = fmaxf(rmax, __shfl_xor(rmax, m, 64));
            float mn = fmaxf(m_r[r], rmax);
            alpha[r] = exp2f(m_r[r] - mn);   // 0 on first tile
            m_r[r] = mn;
            float rs = 0.f;
#pragma unroll
            for (int n0 = 0; n0 < 4; ++n0) {
                float p = exp2f(sc4[n0][r] - mn);
                sc4[n0][r] = p;
                rs += p;
            }
#pragma unroll
            for (int m = 1; m < 16; m <<= 1)
                rs += __shfl_xor(rs, m, 64);
            l_r[r] = l_r[r] * alpha[r] + rs;
        }
#pragma unroll
        for (int d0 = 0; d0 < 8; ++d0)
#pragma unroll
            for (int r = 0; r < 4; ++r) o[d0][r] *= alpha[r];

        // ---- P: C-layout regs -> A-layout via per-wave swizzled LDS ----
#pragma unroll
        for (int n0 = 0; n0 < 4; ++n0) {
            const int G = n0 * 2 + (l16 >> 3);      // granule of col n0*16+l16
            const int cs = l16 & 7;                  // offset within granule
#pragma unroll
            for (int r = 0; r < 4; ++r) {
                const int row  = quad * 4 + r;
                const int slot = G ^ (row & 7);
                Ps[w][row][slot * 8 + cs] = (__bf16)sc4[n0][r];
            }
        }

        // ---- PV: O[16 q][128 d] += P[16][64] * V[64][128] ----
#pragma unroll
        for (int kk = 0; kk < 64; kk += 32) {
            const int Gp    = (kk >> 3) + quad;
            const int slotp = Gp ^ (l16 & 7);
            bf16x8 af = *reinterpret_cast<const bf16x8*>(&Ps[w][l16][slotp * 8]);
#pragma unroll
            for (int d0 = 0; d0 < 8; ++d0) {
                const int row  = d0 * 16 + l16;
                const int slot = Gp ^ (row & 7);
                bf16x8 bf = *reinterpret_cast<const bf16x8*>(&Vt[row * 64 + slot * 8]);
                o[d0] = __builtin_amdgcn_mfma_f32_16x16x32_bf16(af, bf, o[d0], 0, 0, 0);
            }
        }
    }

    // ---- epilogue: normalize, write rows quad*4+r of wave's 16-row strip ----
    float inv[4];
#pragma unroll
    for (int r = 0; r < 4; ++r) inv[r] = 1.f / l_r[r];
#pragma unroll
    for (int d0 = 0; d0 < 8; ++d0)
#pragma unroll
        for (int r = 0; r < 4; ++r) {
            size_t row = (size_t)(b * S_LEN + q0 + w * 16 + quad * 4 + r);
            att[row * DMODEL + h * 128 + d0 * 16 + l16] =
                __float2bfloat16(o[d0][r] * inv[r]);
        }
}

// ---------------------------------------------------------------------------
extern "C" void kernel_launch(void* const* d_in, const int* in_sizes, int n_in,
                              void* d_out, int out_size, void* d_ws, size_t ws_size,
                              hipStream_t stream) {
    const void* x  = d_in[0];
    const void* wq = d_in[1];
    const void* wk = d_in[2];
    const void* wv = d_in[3];
    const void* wo = d_in[4];
    const void* fc = d_in[5];
    const void* fs = d_in[6];
    const unsigned char* mraw = (const unsigned char*)d_in[7];

    const int M = BATCH * S_LEN;                                 // 4096
    // ws (proven 32 MB + 8 KB): control, xq(16M, att aliases), xk(8M), xv(8M).
    char* wsb = (char*)d_ws;
    int* dflag_x  = (int*)wsb;
    int* dflag_fc = (int*)(wsb + 64);
    unsigned char* mnorm = (unsigned char*)(wsb + 128);
    __hip_bfloat16* xq = (__hip_bfloat16*)(wsb + 8192);
    __hip_bfloat16* xk = xq + (size_t)M * DMODEL;
    __hip_bfloat16* xv = xk + (size_t)M * KVD;
    __hip_bfloat16* att = xq;                       // alias (safe, see attn)
    __hip_bfloat16* wob = xk;                       // reuses xk after attn

    // d_out (32 MB f32) as staging scratch before its final write.
    char* dob = (char*)d_out;
    __bf16* xb  = (__bf16*)dob;
    __bf16* wqb = (__bf16*)(dob + (16u << 20));
    __bf16* wkb = (__bf16*)(dob + (24u << 20));
    __bf16* wvb = (__bf16*)(dob + (28u << 20));
    __hip_bfloat16* vt = (__hip_bfloat16*)d_out;

    hipLaunchKernelGGL(sniff_x_kernel, dim3(1), dim3(256), 0, stream,
                       (const unsigned*)x, dflag_x);
    hipLaunchKernelGGL(sniff_fc_kernel, dim3(1), dim3(64), 0, stream,
                       (const unsigned*)fc, dflag_fc);
    hipLaunchKernelGGL(mask_norm_kernel, dim3(1), dim3(256), 0, stream,
                       mraw, mnorm, BATCH * S_LEN);

    hipLaunchKernelGGL(conv_bf16_kernel, dim3((M * DMODEL / 8) / 256), dim3(256), 0, stream,
                       x, xb, M * DMODEL / 8, dflag_x);
    hipLaunchKernelGGL(conv_bf16_kernel, dim3((DMODEL * DMODEL / 8) / 256), dim3(256), 0, stream,
                       wq, wqb, DMODEL * DMODEL / 8, dflag_x);
    hipLaunchKernelGGL(conv_bf16_kernel, dim3((KVD * DMODEL / 8) / 256), dim3(256), 0, stream,
                       wk, wkb, KVD * DMODEL / 8, dflag_x);
    hipLaunchKernelGGL(conv_bf16_kernel, dim3((KVD * DMODEL / 8) / 256), dim3(256), 0, stream,
                       wv, wvb, KVD * DMODEL / 8, dflag_x);

    hipLaunchKernelGGL((gemm_bt_async<true>), dim3(M / 128, DMODEL / 128), dim3(256), 0, stream,
                       xb, wqb, (void*)xq, M, DMODEL, DMODEL);
    hipLaunchKernelGGL((gemm_bt_async<true>), dim3(M / 128, KVD / 128), dim3(256), 0, stream,
                       xb, wkb, (void*)xk, M, KVD, DMODEL);
    hipLaunchKernelGGL((gemm_bt_async<true>), dim3(M / 128, KVD / 128), dim3(256), 0, stream,
                       xb, wvb, (void*)xv, M, KVD, DMODEL);

    int npq = M * NHQ * (HD_DIM / 2);
    int npk = M * NKV_H * (HD_DIM / 2);
    hipLaunchKernelGGL(rope_kernel, dim3(npq / 256), dim3(256), 0, stream,
                       xq, fc, fs, dflag_fc, NHQ, npq);
    hipLaunchKernelGGL(rope_kernel, dim3(npk / 256), dim3(256), 0, stream,
                       xk, fc, fs, dflag_fc, NKV_H, npk);

    hipLaunchKernelGGL(transpose_v_kernel, dim3(S_LEN / 32, HD_DIM / 32, BATCH * NKV_H),
                       dim3(256), 0, stream, xv, vt);

    hipLaunchKernelGGL(attn_mfma2_kernel, dim3(BATCH * NHQ * (S_LEN / 64)), dim3(256), 0, stream,
                       xq, xk, vt, mnorm, att);

    hipLaunchKernelGGL(conv_bf16_kernel, dim3((DMODEL * DMODEL / 8) / 256), dim3(256), 0, stream,
                       wo, (__bf16*)wob, DMODEL * DMODEL / 8, dflag_x);
    hipLaunchKernelGGL((gemm_bt_async<false>), dim3(M / 128, DMODEL / 128), dim3(256), 0, stream,
                       (const __bf16*)att, (const __bf16*)wob, d_out, M, DMODEL, DMODEL);
}